// Round 2
// baseline (411.768 us; speedup 1.0000x reference)
//
#include <hip/hip_runtime.h>

typedef __attribute__((ext_vector_type(4))) float  f32x4;
typedef __attribute__((ext_vector_type(8))) short  s16x8;
typedef __attribute__((ext_vector_type(4))) short  s16x4;

__device__ __forceinline__ short f2bf(float f) {
    unsigned u = __builtin_bit_cast(unsigned, f);
    u += 0x7fff + ((u >> 16) & 1);
    return (short)(u >> 16);
}

__device__ __forceinline__ void load_lds16(const void* g, void* l) {
    __builtin_amdgcn_global_load_lds(
        (const __attribute__((address_space(1))) unsigned int*)g,
        (__attribute__((address_space(3))) unsigned int*)l, 16, 0, 0);
}

// ---------------- transpose + cast: W[K][N] f32 -> Wt[N][K] bf16 ----------------
__global__ __launch_bounds__(256) void transpose_cast(const float* __restrict__ W,
                                                      short* __restrict__ Wt,
                                                      int K, int N) {
    __shared__ float t[32][33];
    int n0 = blockIdx.x * 32, k0 = blockIdx.y * 32;
    int tx = threadIdx.x & 31, ty = threadIdx.x >> 5;  // 32 x 8
#pragma unroll
    for (int i = 0; i < 4; i++)
        t[ty + 8 * i][tx] = W[(size_t)(k0 + ty + 8 * i) * N + n0 + tx];
    __syncthreads();
#pragma unroll
    for (int i = 0; i < 4; i++)
        Wt[(size_t)(n0 + ty + 8 * i) * K + k0 + tx] = f2bf(t[tx][ty + 8 * i]);
}

// ---------------- LayerNorm: f32 [rows][1024] -> bf16 ----------------
__global__ __launch_bounds__(256) void ln_kernel(const float* __restrict__ x,
                                                 const float* __restrict__ w,
                                                 const float* __restrict__ b,
                                                 short* __restrict__ out) {
    int row = blockIdx.x;
    int tid = threadIdx.x;
    const float4 v = ((const float4*)(x + (size_t)row * 1024))[tid];
    float s  = v.x + v.y + v.z + v.w;
    float ss = v.x * v.x + v.y * v.y + v.z * v.z + v.w * v.w;
#pragma unroll
    for (int o = 32; o > 0; o >>= 1) {
        s  += __shfl_down(s, o);
        ss += __shfl_down(ss, o);
    }
    __shared__ float rs[4], rq[4];
    int wave = tid >> 6, lane = tid & 63;
    if (lane == 0) { rs[wave] = s; rq[wave] = ss; }
    __syncthreads();
    float tot = rs[0] + rs[1] + rs[2] + rs[3];
    float tq  = rq[0] + rq[1] + rq[2] + rq[3];
    float mu   = tot * (1.f / 1024.f);
    float var  = tq * (1.f / 1024.f) - mu * mu;
    float rstd = rsqrtf(var + 1e-5f);
    const float4 wv = ((const float4*)w)[tid];
    const float4 bv = ((const float4*)b)[tid];
    s16x4 o;
    o[0] = f2bf((v.x - mu) * rstd * wv.x + bv.x);
    o[1] = f2bf((v.y - mu) * rstd * wv.y + bv.y);
    o[2] = f2bf((v.z - mu) * rstd * wv.z + bv.z);
    o[3] = f2bf((v.w - mu) * rstd * wv.w + bv.w);
    ((s16x4*)(out + (size_t)row * 1024))[tid] = o;
}

// ---------------- GEMM: C[M][N] = A[M][K](bf16) * Bt[N][K](bf16) + bias (+res) (gelu?) ----------------
// 128x128 tile, BK=32, 4 waves (2x2), each wave 64x64 via 4x4 16x16 frags.
template <typename OUT_T, bool GELU, bool RES>
__global__ __launch_bounds__(256) void gemm_bt(const short* __restrict__ A,
                                               const short* __restrict__ Bt,
                                               const float* __restrict__ bias,
                                               const float* __restrict__ res,
                                               OUT_T* __restrict__ C,
                                               int M, int N, int K) {
    __shared__ __align__(16) short As[128 * 32];
    __shared__ __align__(16) short Bs[128 * 32];
    int tid = threadIdx.x;
    int m0 = blockIdx.y * 128, n0 = blockIdx.x * 128;
    int wave = tid >> 6, lane = tid & 63;
    int wr = wave >> 1, wc = wave & 1;
    int g = lane >> 4, q = lane & 15;
    f32x4 acc[4][4] = {};
    const short* Ab = A + (size_t)m0 * K;
    const short* Bb = Bt + (size_t)n0 * K;
    int srow = tid >> 2;
    int scol = (tid & 3) * 8;
    for (int k0 = 0; k0 < K; k0 += 32) {
        __syncthreads();
        load_lds16(Ab + (size_t)srow * K + k0 + scol, As + tid * 8);
        load_lds16(Ab + (size_t)(srow + 64) * K + k0 + scol, As + 2048 + tid * 8);
        load_lds16(Bb + (size_t)srow * K + k0 + scol, Bs + tid * 8);
        load_lds16(Bb + (size_t)(srow + 64) * K + k0 + scol, Bs + 2048 + tid * 8);
        __syncthreads();
        s16x8 a[4], bf[4];
#pragma unroll
        for (int mi = 0; mi < 4; mi++)
            a[mi] = *(const s16x8*)(As + (wr * 64 + mi * 16 + q) * 32 + g * 8);
#pragma unroll
        for (int ni = 0; ni < 4; ni++)
            bf[ni] = *(const s16x8*)(Bs + (wc * 64 + ni * 16 + q) * 32 + g * 8);
#pragma unroll
        for (int mi = 0; mi < 4; mi++)
#pragma unroll
            for (int ni = 0; ni < 4; ni++)
                acc[mi][ni] = __builtin_amdgcn_mfma_f32_16x16x32_bf16(a[mi], bf[ni], acc[mi][ni], 0, 0, 0);
    }
    // epilogue
#pragma unroll
    for (int mi = 0; mi < 4; mi++) {
#pragma unroll
        for (int ni = 0; ni < 4; ni++) {
            int row = m0 + wr * 64 + mi * 16 + g * 4;
            int col = n0 + wc * 64 + ni * 16 + q;
            float bb = bias[col];
#pragma unroll
            for (int r = 0; r < 4; r++) {
                float v = acc[mi][ni][r] + bb;
                if (RES) v += res[(size_t)(row + r) * N + col];
                if (GELU) {
                    float aa = 0.7978845608028654f * (v + 0.044715f * v * v * v);
                    float th = 1.f - 2.f / (__expf(2.f * aa) + 1.f);
                    v = 0.5f * v * (1.f + th);
                }
                if constexpr (sizeof(OUT_T) == 2)
                    C[(size_t)(row + r) * N + col] = f2bf(v);
                else
                    C[(size_t)(row + r) * N + col] = v;
            }
        }
    }
}

// ---------------- Flash attention: qkv bf16 [B*T][3072] -> y bf16 [B*T][1024] ----------------
// grid (T/64, B*H). block 256 = 4 waves; each wave owns 16 q rows.
// swapped QK^T: S^T = mfma(K, Q) so softmax state is lane-local per q row (col = lane&15).
__global__ __launch_bounds__(256) void attn_kernel(const short* __restrict__ qkv,
                                                   short* __restrict__ y) {
    const int T = 2048, C3 = 3072;
    int qt = blockIdx.x;
    int bh = blockIdx.y;
    int b = bh >> 4, h = bh & 15;
    int tid = threadIdx.x, lane = tid & 63, wave = tid >> 6;
    int g = lane >> 4, q = lane & 15;
    const short* base = qkv + (size_t)b * T * C3;
    int qrow = qt * 64 + wave * 16 + q;
    const short* qp = base + (size_t)qrow * C3 + h * 64 + g * 8;
    s16x8 qf0 = *(const s16x8*)qp;
    s16x8 qf1 = *(const s16x8*)(qp + 32);

    __shared__ __align__(16) short Vt[64][72];      // [d][key] padded
    __shared__ __align__(16) short Pl[4][16][72];   // per-wave [q][key] padded

    float mst = -INFINITY, lst = 0.f;
    f32x4 accy[4] = {};
    int vkey = tid >> 2;            // 64 keys
    int vd0 = (tid & 3) * 16;       // 4 threads x 16 dims = full 64 dims

    for (int t = 0; t < 32; ++t) {
        int kv0 = t * 64;
        // S^T = K * Q  (A rows = keys, B cols = q rows)
        f32x4 sc[4];
#pragma unroll
        for (int n = 0; n < 4; n++) {
            const short* kp = base + (size_t)(kv0 + 16 * n + q) * C3 + 1024 + h * 64 + g * 8;
            s16x8 kf0 = *(const s16x8*)kp;
            s16x8 kf1 = *(const s16x8*)(kp + 32);
            f32x4 z = {};
            z = __builtin_amdgcn_mfma_f32_16x16x32_bf16(kf0, qf0, z, 0, 0, 0);
            z = __builtin_amdgcn_mfma_f32_16x16x32_bf16(kf1, qf1, z, 0, 0, 0);
            sc[n] = z * 0.125f;
        }
        // stage V transposed into LDS (prev tile's PV reads done at this barrier)
        __syncthreads();
        {
            const short* vp = base + (size_t)(kv0 + vkey) * C3 + 2048 + h * 64 + vd0;
            s16x8 vv0 = *(const s16x8*)vp;
            s16x8 vv1 = *(const s16x8*)(vp + 8);
#pragma unroll
            for (int j = 0; j < 8; j++) {
                Vt[vd0 + j][vkey]     = vv0[j];
                Vt[vd0 + 8 + j][vkey] = vv1[j];
            }
        }
        // online softmax (per q row = lane&15; keys spread over n, r, and lane>>4)
        float tm = -INFINITY;
#pragma unroll
        for (int n = 0; n < 4; n++)
#pragma unroll
            for (int r = 0; r < 4; r++) tm = fmaxf(tm, sc[n][r]);
        tm = fmaxf(tm, __shfl_xor(tm, 16));
        tm = fmaxf(tm, __shfl_xor(tm, 32));
        float mnew = fmaxf(mst, tm);
        float alpha = __expf(mst - mnew);
        float p[4][4];
        float ps = 0.f;
#pragma unroll
        for (int n = 0; n < 4; n++)
#pragma unroll
            for (int r = 0; r < 4; r++) {
                p[n][r] = __expf(sc[n][r] - mnew);
                ps += p[n][r];
            }
        ps += __shfl_xor(ps, 16);
        ps += __shfl_xor(ps, 32);
        lst = lst * alpha + ps;
        mst = mnew;
        // rescale accumulator rows (acc row = 4g+r; alpha for q-row j lives at lane j)
#pragma unroll
        for (int r = 0; r < 4; r++) {
            float ar = __shfl(alpha, 4 * g + r);
#pragma unroll
            for (int n = 0; n < 4; n++) accy[n][r] *= ar;
        }
        // write P (bf16) to wave-private LDS: Pl[wave][q][key], key = 16n+4g+r
#pragma unroll
        for (int n = 0; n < 4; n++) {
            s16x4 pw;
#pragma unroll
            for (int r = 0; r < 4; r++) pw[r] = f2bf(p[n][r]);
            *(s16x4*)&Pl[wave][q][16 * n + 4 * g] = pw;
        }
        __syncthreads();  // Vt staged
        // PV: A = P (rows = q), B = Vt (cols = d)
        s16x8 pa0 = *(const s16x8*)&Pl[wave][q][8 * g];
        s16x8 pa1 = *(const s16x8*)&Pl[wave][q][32 + 8 * g];
#pragma unroll
        for (int n = 0; n < 4; n++) {
            s16x8 v0 = *(const s16x8*)&Vt[16 * n + q][8 * g];
            s16x8 v1 = *(const s16x8*)&Vt[16 * n + q][32 + 8 * g];
            accy[n] = __builtin_amdgcn_mfma_f32_16x16x32_bf16(pa0, v0, accy[n], 0, 0, 0);
            accy[n] = __builtin_amdgcn_mfma_f32_16x16x32_bf16(pa1, v1, accy[n], 0, 0, 0);
        }
    }
    // write y
    short* yb = y + ((size_t)b * T + qt * 64 + wave * 16) * 1024 + h * 64;
#pragma unroll
    for (int r = 0; r < 4; r++) {
        float linv = 1.f / __shfl(lst, 4 * g + r);
#pragma unroll
        for (int n = 0; n < 4; n++)
            yb[(size_t)(4 * g + r) * 1024 + 16 * n + q] = f2bf(accy[n][r] * linv);
    }
}

extern "C" void kernel_launch(void* const* d_in, const int* in_sizes, int n_in,
                              void* d_out, int out_size, void* d_ws, size_t ws_size,
                              hipStream_t stream) {
    const float* x           = (const float*)d_in[0];
    const float* ln1_w       = (const float*)d_in[1];
    const float* ln1_b       = (const float*)d_in[2];
    const float* attn_w      = (const float*)d_in[3];
    const float* attn_b      = (const float*)d_in[4];
    const float* attn_proj_w = (const float*)d_in[5];
    const float* attn_proj_b = (const float*)d_in[6];
    const float* ln2_w       = (const float*)d_in[7];
    const float* ln2_b       = (const float*)d_in[8];
    const float* fc_w        = (const float*)d_in[9];
    const float* fc_b        = (const float*)d_in[10];
    const float* mlp_proj_w  = (const float*)d_in[11];
    const float* mlp_proj_b  = (const float*)d_in[12];

    const int M = 4096;  // B*T

    size_t off = 0;
    char* wsb = (char*)d_ws;
    auto alloc = [&](size_t bytes) {
        void* p = wsb + off;
        off += (bytes + 255) & ~(size_t)255;
        return p;
    };
    // weights: 24 MB
    short* wt_attn  = (short*)alloc(3072ull * 1024 * 2);
    short* wt_proj  = (short*)alloc(1024ull * 1024 * 2);
    short* wt_fc    = (short*)alloc(4096ull * 1024 * 2);
    short* wt_mproj = (short*)alloc(1024ull * 4096 * 2);
    // activations
    short* h1       = (short*)alloc((size_t)M * 1024 * 2);   // 8 MB (LN out; reused LN2)
    short* qkvb     = (short*)alloc((size_t)M * 3072 * 2);   // 24 MB
    short* yb       = (short*)alloc((size_t)M * 1024 * 2);   // 8 MB
    float* x1       = (float*)alloc((size_t)M * 1024 * 4);   // 16 MB
    // h2 (32 MB) aliases qkvb+yb: both dead before the fc GEMM writes h2,
    // and every buffer is fully rewritten each call before any read.
    short* h2       = qkvb;

    // weight transposes (f32 [K][N] -> bf16 [N][K])
    transpose_cast<<<dim3(3072 / 32, 1024 / 32), 256, 0, stream>>>(attn_w, wt_attn, 1024, 3072);
    transpose_cast<<<dim3(1024 / 32, 1024 / 32), 256, 0, stream>>>(attn_proj_w, wt_proj, 1024, 1024);
    transpose_cast<<<dim3(4096 / 32, 1024 / 32), 256, 0, stream>>>(fc_w, wt_fc, 1024, 4096);
    transpose_cast<<<dim3(1024 / 32, 4096 / 32), 256, 0, stream>>>(mlp_proj_w, wt_mproj, 4096, 1024);

    // LN1
    ln_kernel<<<M, 256, 0, stream>>>(x, ln1_w, ln1_b, h1);
    // qkv = h1 @ attn_w + attn_b
    gemm_bt<short, false, false><<<dim3(3072 / 128, M / 128), 256, 0, stream>>>(
        h1, wt_attn, attn_b, nullptr, qkvb, M, 3072, 1024);
    // attention
    attn_kernel<<<dim3(2048 / 64, 32), 256, 0, stream>>>(qkvb, yb);
    // x1 = x + y @ attn_proj_w + attn_proj_b
    gemm_bt<float, false, true><<<dim3(1024 / 128, M / 128), 256, 0, stream>>>(
        yb, wt_proj, attn_proj_b, x, x1, M, 1024, 1024);
    // LN2
    ln_kernel<<<M, 256, 0, stream>>>(x1, ln2_w, ln2_b, h1);
    // h2 = gelu(h1 @ fc_w + fc_b)
    gemm_bt<short, true, false><<<dim3(4096 / 128, M / 128), 256, 0, stream>>>(
        h1, wt_fc, fc_b, nullptr, h2, M, 4096, 1024);
    // out = x1 + h2 @ mlp_proj_w + mlp_proj_b
    gemm_bt<float, false, true><<<dim3(1024 / 128, M / 128), 256, 0, stream>>>(
        h2, wt_mproj, mlp_proj_b, x1, (float*)d_out, M, 1024, 4096);
}

// Round 3
// 336.834 us; speedup vs baseline: 1.2225x; 1.2225x over previous
//
#include <hip/hip_runtime.h>

typedef __attribute__((ext_vector_type(4))) float  f32x4;
typedef __attribute__((ext_vector_type(8))) short  s16x8;
typedef __attribute__((ext_vector_type(4))) short  s16x4;

__device__ __forceinline__ short f2bf(float f) {
    unsigned u = __builtin_bit_cast(unsigned, f);
    u += 0x7fff + ((u >> 16) & 1);
    return (short)(u >> 16);
}

__device__ __forceinline__ void load_lds16(const void* g, void* l) {
    __builtin_amdgcn_global_load_lds(
        (const __attribute__((address_space(1))) unsigned int*)g,
        (__attribute__((address_space(3))) unsigned int*)l, 16, 0, 0);
}

// ---------------- transpose + cast: W[K][N] f32 -> Wt[N][K] bf16 ----------------
__global__ __launch_bounds__(256) void transpose_cast(const float* __restrict__ W,
                                                      short* __restrict__ Wt,
                                                      int K, int N) {
    __shared__ float t[32][33];
    int n0 = blockIdx.x * 32, k0 = blockIdx.y * 32;
    int tx = threadIdx.x & 31, ty = threadIdx.x >> 5;  // 32 x 8
#pragma unroll
    for (int i = 0; i < 4; i++)
        t[ty + 8 * i][tx] = W[(size_t)(k0 + ty + 8 * i) * N + n0 + tx];
    __syncthreads();
#pragma unroll
    for (int i = 0; i < 4; i++)
        Wt[(size_t)(n0 + ty + 8 * i) * K + k0 + tx] = f2bf(t[tx][ty + 8 * i]);
}

// ---------------- LayerNorm: f32 [rows][1024] -> bf16 ----------------
__global__ __launch_bounds__(256) void ln_kernel(const float* __restrict__ x,
                                                 const float* __restrict__ w,
                                                 const float* __restrict__ b,
                                                 short* __restrict__ out) {
    int row = blockIdx.x;
    int tid = threadIdx.x;
    const float4 v = ((const float4*)(x + (size_t)row * 1024))[tid];
    float s  = v.x + v.y + v.z + v.w;
    float ss = v.x * v.x + v.y * v.y + v.z * v.z + v.w * v.w;
#pragma unroll
    for (int o = 32; o > 0; o >>= 1) {
        s  += __shfl_down(s, o);
        ss += __shfl_down(ss, o);
    }
    __shared__ float rs[4], rq[4];
    int wave = tid >> 6, lane = tid & 63;
    if (lane == 0) { rs[wave] = s; rq[wave] = ss; }
    __syncthreads();
    float tot = rs[0] + rs[1] + rs[2] + rs[3];
    float tq  = rq[0] + rq[1] + rq[2] + rq[3];
    float mu   = tot * (1.f / 1024.f);
    float var  = tq * (1.f / 1024.f) - mu * mu;
    float rstd = rsqrtf(var + 1e-5f);
    const float4 wv = ((const float4*)w)[tid];
    const float4 bv = ((const float4*)b)[tid];
    s16x4 o;
    o[0] = f2bf((v.x - mu) * rstd * wv.x + bv.x);
    o[1] = f2bf((v.y - mu) * rstd * wv.y + bv.y);
    o[2] = f2bf((v.z - mu) * rstd * wv.z + bv.z);
    o[3] = f2bf((v.w - mu) * rstd * wv.w + bv.w);
    ((s16x4*)(out + (size_t)row * 1024))[tid] = o;
}

// ---------------- GEMM: C[M][N] = A[M][K](bf16) * Bt[N][K](bf16) + bias (+res) (gelu?) ----------------
template <typename OUT_T, bool GELU, bool RES>
__global__ __launch_bounds__(256) void gemm_bt(const short* __restrict__ A,
                                               const short* __restrict__ Bt,
                                               const float* __restrict__ bias,
                                               const float* __restrict__ res,
                                               OUT_T* __restrict__ C,
                                               int M, int N, int K) {
    __shared__ __align__(16) short As[128 * 32];
    __shared__ __align__(16) short Bs[128 * 32];
    int tid = threadIdx.x;
    int m0 = blockIdx.y * 128, n0 = blockIdx.x * 128;
    int wave = tid >> 6, lane = tid & 63;
    int wr = wave >> 1, wc = wave & 1;
    int g = lane >> 4, q = lane & 15;
    f32x4 acc[4][4] = {};
    const short* Ab = A + (size_t)m0 * K;
    const short* Bb = Bt + (size_t)n0 * K;
    int srow = tid >> 2;
    int scol = (tid & 3) * 8;
    for (int k0 = 0; k0 < K; k0 += 32) {
        __syncthreads();
        load_lds16(Ab + (size_t)srow * K + k0 + scol, As + tid * 8);
        load_lds16(Ab + (size_t)(srow + 64) * K + k0 + scol, As + 2048 + tid * 8);
        load_lds16(Bb + (size_t)srow * K + k0 + scol, Bs + tid * 8);
        load_lds16(Bb + (size_t)(srow + 64) * K + k0 + scol, Bs + 2048 + tid * 8);
        __syncthreads();
        s16x8 a[4], bf[4];
#pragma unroll
        for (int mi = 0; mi < 4; mi++)
            a[mi] = *(const s16x8*)(As + (wr * 64 + mi * 16 + q) * 32 + g * 8);
#pragma unroll
        for (int ni = 0; ni < 4; ni++)
            bf[ni] = *(const s16x8*)(Bs + (wc * 64 + ni * 16 + q) * 32 + g * 8);
#pragma unroll
        for (int mi = 0; mi < 4; mi++)
#pragma unroll
            for (int ni = 0; ni < 4; ni++)
                acc[mi][ni] = __builtin_amdgcn_mfma_f32_16x16x32_bf16(a[mi], bf[ni], acc[mi][ni], 0, 0, 0);
    }
#pragma unroll
    for (int mi = 0; mi < 4; mi++) {
#pragma unroll
        for (int ni = 0; ni < 4; ni++) {
            int row = m0 + wr * 64 + mi * 16 + g * 4;
            int col = n0 + wc * 64 + ni * 16 + q;
            float bb = bias[col];
#pragma unroll
            for (int r = 0; r < 4; r++) {
                float v = acc[mi][ni][r] + bb;
                if (RES) v += res[(size_t)(row + r) * N + col];
                if (GELU) {
                    float aa = 0.7978845608028654f * (v + 0.044715f * v * v * v);
                    float th = 1.f - 2.f / (__expf(2.f * aa) + 1.f);
                    v = 0.5f * v * (1.f + th);
                }
                if constexpr (sizeof(OUT_T) == 2)
                    C[(size_t)(row + r) * N + col] = f2bf(v);
                else
                    C[(size_t)(row + r) * N + col] = v;
            }
        }
    }
}

// ---------------- Flash attention v2 ----------------
// grid (32, 32), block 256 = 4 waves; each wave 16 q rows; KV tile 64.
// K staged via global_load_lds with chunk-XOR swizzle (pre-swizzled global src).
// V transposed in LDS with chunk-XOR layout (conflict-free scalar writes).
// exp2-domain softmax with defer-max (THR=8).
__global__ __launch_bounds__(256) void attn_kernel(const short* __restrict__ qkv,
                                                   short* __restrict__ y) {
    const int T = 2048, C3 = 3072;
    int qt = blockIdx.x;
    int bh = blockIdx.y;
    int b = bh >> 4, h = bh & 15;
    int tid = threadIdx.x, lane = tid & 63, wave = tid >> 6;
    int g = lane >> 4, q = lane & 15;
    const short* base = qkv + (size_t)b * T * C3;
    const short* Kb = base + 1024 + h * 64;
    const short* Vb = base + 2048 + h * 64;

    int qrow = qt * 64 + wave * 16 + q;
    const short* qp = base + (size_t)qrow * C3 + h * 64 + g * 8;
    s16x8 qf0 = *(const s16x8*)qp;
    s16x8 qf1 = *(const s16x8*)(qp + 32);

    __shared__ __align__(16) short Ks[64 * 64];     // swizzled chunks, 8 KB
    __shared__ __align__(16) short Vt[64][72];      // [d][key], chunk-XOR cols
    __shared__ __align__(16) short Pl[4][16][72];   // per-wave P

    const float SCL = 0.125f * 1.4426950408889634f;  // 1/sqrt(64) * log2(e)

    float mst = -INFINITY, lst = 0.f;
    f32x4 accy[4] = {};

    // V staging mapping: thread covers key vkey, dims [vd0, vd0+16)
    int vkey = tid >> 2;
    int vd0 = (tid & 3) * 16;
    // Vt element (d, k) stored at col ((k>>3) ^ ((d>>4)&3))*8 + (k&7); (d>>4)&3 == tid&3 here
    int vcol = (((vkey >> 3) ^ (tid & 3)) << 3) + (vkey & 7);

    // K staging mapping: LDS chunk ci holds global chunk (ci&7) ^ (k&7), k = ci>>3
    int kst0 = tid >> 3, kcp = tid & 7;

    // prologue: V(0) into regs
    s16x8 vv0, vv1;
    {
        const short* vp = Vb + (size_t)vkey * C3 + vd0;
        vv0 = *(const s16x8*)vp;
        vv1 = *(const s16x8*)(vp + 8);
    }

    for (int t = 0; t < 32; ++t) {
        int kv0 = t << 6;
        __syncthreads();  // prior tile's Ks/Vt reads complete
        // stage K(t) async (pre-swizzled source, linear LDS dest)
        load_lds16(Kb + (size_t)(kv0 + kst0) * C3 + ((kcp ^ (kst0 & 7)) << 3),
                   Ks + tid * 8);
        load_lds16(Kb + (size_t)(kv0 + kst0 + 32) * C3 + ((kcp ^ ((kst0 + 32) & 7)) << 3),
                   Ks + (tid + 256) * 8);
        // write V(t) transpose from regs (conflict-free via vcol XOR)
#pragma unroll
        for (int j = 0; j < 8; j++) {
            Vt[vd0 + j][vcol]     = vv0[j];
            Vt[vd0 + 8 + j][vcol] = vv1[j];
        }
        __syncthreads();  // Ks + Vt ready
        // prefetch V(t+1) into regs: latency hides under this tile's compute
        if (t < 31) {
            const short* vp = Vb + (size_t)(kv0 + 64 + vkey) * C3 + vd0;
            vv0 = *(const s16x8*)vp;
            vv1 = *(const s16x8*)(vp + 8);
        }
        // S^T = K * Q from LDS (A = K rows; swizzled chunk reads, ~2-way)
        f32x4 sc[4];
#pragma unroll
        for (int n = 0; n < 4; n++) {
            int kr = 16 * n + q;
            const short* kb = Ks + kr * 64;
            int sw = kr & 7;
            s16x8 kf0 = *(const s16x8*)(kb + ((g ^ sw) << 3));
            s16x8 kf1 = *(const s16x8*)(kb + (((4 + g) ^ sw) << 3));
            f32x4 z = {};
            z = __builtin_amdgcn_mfma_f32_16x16x32_bf16(kf0, qf0, z, 0, 0, 0);
            z = __builtin_amdgcn_mfma_f32_16x16x32_bf16(kf1, qf1, z, 0, 0, 0);
            sc[n] = z * SCL;
        }
        // online softmax in exp2 domain (per q row = lane&15)
        float tm = -INFINITY;
#pragma unroll
        for (int n = 0; n < 4; n++)
#pragma unroll
            for (int r = 0; r < 4; r++) tm = fmaxf(tm, sc[n][r]);
        tm = fmaxf(tm, __shfl_xor(tm, 16));
        tm = fmaxf(tm, __shfl_xor(tm, 32));
        if (!__all(tm <= mst + 8.f)) {   // defer-max: rescale only on big growth
            float mnew = fmaxf(mst, tm);
            float alpha = exp2f(mst - mnew);
            lst *= alpha;
#pragma unroll
            for (int r = 0; r < 4; r++) {
                float ar = __shfl(alpha, 4 * g + r);
#pragma unroll
                for (int n = 0; n < 4; n++) accy[n][r] *= ar;
            }
            mst = mnew;
        }
        float p[4][4];
        float ps = 0.f;
#pragma unroll
        for (int n = 0; n < 4; n++)
#pragma unroll
            for (int r = 0; r < 4; r++) {
                p[n][r] = exp2f(sc[n][r] - mst);  // bounded by 2^8
                ps += p[n][r];
            }
        ps += __shfl_xor(ps, 16);
        ps += __shfl_xor(ps, 32);
        lst += ps;
        // P -> wave-private LDS (no barrier needed; same-wave DS ordering)
#pragma unroll
        for (int n = 0; n < 4; n++) {
            s16x4 pw;
#pragma unroll
            for (int r = 0; r < 4; r++) pw[r] = f2bf(p[n][r]);
            *(s16x4*)&Pl[wave][q][16 * n + 4 * g] = pw;
        }
        s16x8 pa0 = *(const s16x8*)&Pl[wave][q][8 * g];
        s16x8 pa1 = *(const s16x8*)&Pl[wave][q][32 + 8 * g];
        // PV: A = P, B = Vt (chunk-XOR reads)
#pragma unroll
        for (int n = 0; n < 4; n++) {
            s16x8 v0 = *(const s16x8*)&Vt[16 * n + q][(g ^ n) << 3];
            s16x8 v1 = *(const s16x8*)&Vt[16 * n + q][32 + ((g ^ n) << 3)];
            accy[n] = __builtin_amdgcn_mfma_f32_16x16x32_bf16(pa0, v0, accy[n], 0, 0, 0);
            accy[n] = __builtin_amdgcn_mfma_f32_16x16x32_bf16(pa1, v1, accy[n], 0, 0, 0);
        }
    }
    // write y
    short* yb = y + ((size_t)b * T + qt * 64 + wave * 16) * 1024 + h * 64;
#pragma unroll
    for (int r = 0; r < 4; r++) {
        float linv = 1.f / __shfl(lst, 4 * g + r);
#pragma unroll
        for (int n = 0; n < 4; n++)
            yb[(size_t)(4 * g + r) * 1024 + 16 * n + q] = f2bf(accy[n][r] * linv);
    }
}

extern "C" void kernel_launch(void* const* d_in, const int* in_sizes, int n_in,
                              void* d_out, int out_size, void* d_ws, size_t ws_size,
                              hipStream_t stream) {
    const float* x           = (const float*)d_in[0];
    const float* ln1_w       = (const float*)d_in[1];
    const float* ln1_b       = (const float*)d_in[2];
    const float* attn_w      = (const float*)d_in[3];
    const float* attn_b      = (const float*)d_in[4];
    const float* attn_proj_w = (const float*)d_in[5];
    const float* attn_proj_b = (const float*)d_in[6];
    const float* ln2_w       = (const float*)d_in[7];
    const float* ln2_b       = (const float*)d_in[8];
    const float* fc_w        = (const float*)d_in[9];
    const float* fc_b        = (const float*)d_in[10];
    const float* mlp_proj_w  = (const float*)d_in[11];
    const float* mlp_proj_b  = (const float*)d_in[12];

    const int M = 4096;  // B*T

    size_t off = 0;
    char* wsb = (char*)d_ws;
    auto alloc = [&](size_t bytes) {
        void* p = wsb + off;
        off += (bytes + 255) & ~(size_t)255;
        return p;
    };
    short* wt_attn  = (short*)alloc(3072ull * 1024 * 2);
    short* wt_proj  = (short*)alloc(1024ull * 1024 * 2);
    short* wt_fc    = (short*)alloc(4096ull * 1024 * 2);
    short* wt_mproj = (short*)alloc(1024ull * 4096 * 2);
    short* h1       = (short*)alloc((size_t)M * 1024 * 2);
    short* qkvb     = (short*)alloc((size_t)M * 3072 * 2);
    short* yb       = (short*)alloc((size_t)M * 1024 * 2);
    float* x1       = (float*)alloc((size_t)M * 1024 * 4);
    short* h2       = qkvb;  // aliases qkv+y region (dead by fc GEMM)

    transpose_cast<<<dim3(3072 / 32, 1024 / 32), 256, 0, stream>>>(attn_w, wt_attn, 1024, 3072);
    transpose_cast<<<dim3(1024 / 32, 1024 / 32), 256, 0, stream>>>(attn_proj_w, wt_proj, 1024, 1024);
    transpose_cast<<<dim3(4096 / 32, 1024 / 32), 256, 0, stream>>>(fc_w, wt_fc, 1024, 4096);
    transpose_cast<<<dim3(1024 / 32, 4096 / 32), 256, 0, stream>>>(mlp_proj_w, wt_mproj, 4096, 1024);

    ln_kernel<<<M, 256, 0, stream>>>(x, ln1_w, ln1_b, h1);
    gemm_bt<short, false, false><<<dim3(3072 / 128, M / 128), 256, 0, stream>>>(
        h1, wt_attn, attn_b, nullptr, qkvb, M, 3072, 1024);
    attn_kernel<<<dim3(2048 / 64, 32), 256, 0, stream>>>(qkvb, yb);
    gemm_bt<float, false, true><<<dim3(1024 / 128, M / 128), 256, 0, stream>>>(
        yb, wt_proj, attn_proj_b, x, x1, M, 1024, 1024);
    ln_kernel<<<M, 256, 0, stream>>>(x1, ln2_w, ln2_b, h1);
    gemm_bt<short, true, false><<<dim3(4096 / 128, M / 128), 256, 0, stream>>>(
        h1, wt_fc, fc_b, nullptr, h2, M, 4096, 1024);
    gemm_bt<float, false, true><<<dim3(1024 / 128, M / 128), 256, 0, stream>>>(
        h2, wt_mproj, mlp_proj_b, x1, (float*)d_out, M, 1024, 4096);
}

// Round 4
// 326.175 us; speedup vs baseline: 1.2624x; 1.0327x over previous
//
#include <hip/hip_runtime.h>

typedef __attribute__((ext_vector_type(4))) float  f32x4;
typedef __attribute__((ext_vector_type(8))) short  s16x8;
typedef __attribute__((ext_vector_type(4))) short  s16x4;

__device__ __forceinline__ short f2bf(float f) {
    unsigned u = __builtin_bit_cast(unsigned, f);
    u += 0x7fff + ((u >> 16) & 1);
    return (short)(u >> 16);
}

__device__ __forceinline__ void load_lds16(const void* g, void* l) {
    __builtin_amdgcn_global_load_lds(
        (const __attribute__((address_space(1))) unsigned int*)g,
        (__attribute__((address_space(3))) unsigned int*)l, 16, 0, 0);
}

// ---------------- transpose + cast: W[K][N] f32 -> Wt[N][K] bf16 ----------------
__global__ __launch_bounds__(256) void transpose_cast(const float* __restrict__ W,
                                                      short* __restrict__ Wt,
                                                      int K, int N) {
    __shared__ float t[32][33];
    int n0 = blockIdx.x * 32, k0 = blockIdx.y * 32;
    int tx = threadIdx.x & 31, ty = threadIdx.x >> 5;  // 32 x 8
#pragma unroll
    for (int i = 0; i < 4; i++)
        t[ty + 8 * i][tx] = W[(size_t)(k0 + ty + 8 * i) * N + n0 + tx];
    __syncthreads();
#pragma unroll
    for (int i = 0; i < 4; i++)
        Wt[(size_t)(n0 + ty + 8 * i) * K + k0 + tx] = f2bf(t[tx][ty + 8 * i]);
}

// ---------------- V transpose: qkv V-part [b][token][h*64+d] -> Vtg [(b*16+h)*64+d][token] ----------------
__global__ __launch_bounds__(256) void vtrans_kernel(const short* __restrict__ qkv,
                                                     short* __restrict__ Vtg) {
    const int T = 2048, C3 = 3072;
    __shared__ short tl[32][33];
    int bh = blockIdx.y >> 1;
    int b = bh >> 4, h = bh & 15;
    int dh = (blockIdx.y & 1) * 32;
    int t0 = blockIdx.x * 32;
    int tx = threadIdx.x & 31, ty = threadIdx.x >> 5;
    const short* src = qkv + (size_t)b * T * C3 + 2048 + h * 64 + dh;
#pragma unroll
    for (int i = 0; i < 4; i++)
        tl[ty + 8 * i][tx] = src[(size_t)(t0 + ty + 8 * i) * C3 + tx];
    __syncthreads();
#pragma unroll
    for (int i = 0; i < 4; i++)
        Vtg[((size_t)bh * 64 + dh + ty + 8 * i) * T + t0 + tx] = tl[tx][ty + 8 * i];
}

// ---------------- LayerNorm: f32 [rows][1024] -> bf16 ----------------
__global__ __launch_bounds__(256) void ln_kernel(const float* __restrict__ x,
                                                 const float* __restrict__ w,
                                                 const float* __restrict__ b,
                                                 short* __restrict__ out) {
    int row = blockIdx.x;
    int tid = threadIdx.x;
    const float4 v = ((const float4*)(x + (size_t)row * 1024))[tid];
    float s  = v.x + v.y + v.z + v.w;
    float ss = v.x * v.x + v.y * v.y + v.z * v.z + v.w * v.w;
#pragma unroll
    for (int o = 32; o > 0; o >>= 1) {
        s  += __shfl_down(s, o);
        ss += __shfl_down(ss, o);
    }
    __shared__ float rs[4], rq[4];
    int wave = tid >> 6, lane = tid & 63;
    if (lane == 0) { rs[wave] = s; rq[wave] = ss; }
    __syncthreads();
    float tot = rs[0] + rs[1] + rs[2] + rs[3];
    float tq  = rq[0] + rq[1] + rq[2] + rq[3];
    float mu   = tot * (1.f / 1024.f);
    float var  = tq * (1.f / 1024.f) - mu * mu;
    float rstd = rsqrtf(var + 1e-5f);
    const float4 wv = ((const float4*)w)[tid];
    const float4 bv = ((const float4*)b)[tid];
    s16x4 o;
    o[0] = f2bf((v.x - mu) * rstd * wv.x + bv.x);
    o[1] = f2bf((v.y - mu) * rstd * wv.y + bv.y);
    o[2] = f2bf((v.z - mu) * rstd * wv.z + bv.z);
    o[3] = f2bf((v.w - mu) * rstd * wv.w + bv.w);
    ((s16x4*)(out + (size_t)row * 1024))[tid] = o;
}

// ---------------- GEMM: C[M][N] = A[M][K](bf16) * Bt[N][K](bf16) + bias (+res) (gelu?) ----------------
// SCALE_Q: multiply cols [0,1024) by 0.125*log2(e) (pre-scaled Q for exp2-domain attention).
template <typename OUT_T, bool GELU, bool RES, bool SCALE_Q>
__global__ __launch_bounds__(256) void gemm_bt(const short* __restrict__ A,
                                               const short* __restrict__ Bt,
                                               const float* __restrict__ bias,
                                               const float* __restrict__ res,
                                               OUT_T* __restrict__ C,
                                               int M, int N, int K) {
    __shared__ __align__(16) short As[128 * 32];
    __shared__ __align__(16) short Bs[128 * 32];
    int tid = threadIdx.x;
    int m0 = blockIdx.y * 128, n0 = blockIdx.x * 128;
    int wave = tid >> 6, lane = tid & 63;
    int wr = wave >> 1, wc = wave & 1;
    int g = lane >> 4, q = lane & 15;
    f32x4 acc[4][4] = {};
    const short* Ab = A + (size_t)m0 * K;
    const short* Bb = Bt + (size_t)n0 * K;
    int srow = tid >> 2;
    int scol = (tid & 3) * 8;
    for (int k0 = 0; k0 < K; k0 += 32) {
        __syncthreads();
        load_lds16(Ab + (size_t)srow * K + k0 + scol, As + tid * 8);
        load_lds16(Ab + (size_t)(srow + 64) * K + k0 + scol, As + 2048 + tid * 8);
        load_lds16(Bb + (size_t)srow * K + k0 + scol, Bs + tid * 8);
        load_lds16(Bb + (size_t)(srow + 64) * K + k0 + scol, Bs + 2048 + tid * 8);
        __syncthreads();
        s16x8 a[4], bf[4];
#pragma unroll
        for (int mi = 0; mi < 4; mi++)
            a[mi] = *(const s16x8*)(As + (wr * 64 + mi * 16 + q) * 32 + g * 8);
#pragma unroll
        for (int ni = 0; ni < 4; ni++)
            bf[ni] = *(const s16x8*)(Bs + (wc * 64 + ni * 16 + q) * 32 + g * 8);
#pragma unroll
        for (int mi = 0; mi < 4; mi++)
#pragma unroll
            for (int ni = 0; ni < 4; ni++)
                acc[mi][ni] = __builtin_amdgcn_mfma_f32_16x16x32_bf16(a[mi], bf[ni], acc[mi][ni], 0, 0, 0);
    }
#pragma unroll
    for (int mi = 0; mi < 4; mi++) {
#pragma unroll
        for (int ni = 0; ni < 4; ni++) {
            int row = m0 + wr * 64 + mi * 16 + g * 4;
            int col = n0 + wc * 64 + ni * 16 + q;
            float bb = bias[col];
#pragma unroll
            for (int r = 0; r < 4; r++) {
                float v = acc[mi][ni][r] + bb;
                if (RES) v += res[(size_t)(row + r) * N + col];
                if (GELU) {
                    float aa = 0.7978845608028654f * (v + 0.044715f * v * v * v);
                    float th = 1.f - 2.f / (__expf(2.f * aa) + 1.f);
                    v = 0.5f * v * (1.f + th);
                }
                if (SCALE_Q && col < 1024) v *= 0.18033688011112042f;  // 0.125*log2(e)
                if constexpr (sizeof(OUT_T) == 2)
                    C[(size_t)(row + r) * N + col] = f2bf(v);
                else
                    C[(size_t)(row + r) * N + col] = v;
            }
        }
    }
}

// ---------------- Flash attention v3 ----------------
// 1D grid 1024 blocks (XCD-swizzled), 4 waves; wave = 16 q rows; KV tile 64, double-buffered.
// K and V^T both staged via global_load_lds with chunk-XOR swizzle folded into global src.
// exp2-domain softmax (Q pre-scaled), defer-max THR=8, cvt_pk P conversion.
__global__ __launch_bounds__(256) void attn_kernel(const short* __restrict__ qkv,
                                                   const short* __restrict__ Vtg,
                                                   short* __restrict__ y) {
    const int T = 2048, C3 = 3072;
    int wg = blockIdx.x;
    int mapped = (wg & 7) * 128 + (wg >> 3);   // XCD gets contiguous chunk: 4 heads/XCD
    int bh = mapped >> 5, qt = mapped & 31;
    int b = bh >> 4, h = bh & 15;
    int tid = threadIdx.x, lane = tid & 63, wave = tid >> 6;
    int g = lane >> 4, q = lane & 15;
    const short* base = qkv + (size_t)b * T * C3;

    int qrow = qt * 64 + wave * 16 + q;
    const short* qp = base + (size_t)qrow * C3 + h * 64 + g * 8;
    s16x8 qf0 = *(const s16x8*)qp;
    s16x8 qf1 = *(const s16x8*)(qp + 32);

    __shared__ __align__(16) short Ks[2][64 * 64];
    __shared__ __align__(16) short Vs[2][64 * 64];
    __shared__ __align__(16) short Pl[4][16 * 64];

    // staging: thread -> LDS offset tid*8 (+2048); row srow(+32), chunk sc8.
    // LDS chunk c of row r holds global chunk (c ^ (r&7))  [(r+32)&7 == r&7]
    int srow = tid >> 3, sc8 = tid & 7;
    const short* ksrc = base + 1024 + h * 64 + (size_t)srow * C3 + ((sc8 ^ (srow & 7)) << 3);
    const short* vsrc = Vtg + ((size_t)bh * 64 + srow) * T + ((sc8 ^ (srow & 7)) << 3);

    auto stage = [&](int bi, int t) {
        const short* kp = ksrc + (size_t)(t * 64) * C3;
        load_lds16(kp, &Ks[bi][tid * 8]);
        load_lds16(kp + (size_t)32 * C3, &Ks[bi][tid * 8 + 2048]);
        const short* vp = vsrc + t * 64;
        load_lds16(vp, &Vs[bi][tid * 8]);
        load_lds16(vp + (size_t)32 * T, &Vs[bi][tid * 8 + 2048]);
    };

    float mst = -INFINITY, lst = 0.f;
    f32x4 accy[4] = {};
    int sw = q & 7;
    int s2 = sw << 1;

    stage(0, 0);
    for (int t = 0; t < 32; ++t) {
        int cur = t & 1;
        __syncthreads();               // staged(t) complete; prev reads of buf[cur^1] done
        if (t < 31) stage(cur ^ 1, t + 1);  // flies under this tile's compute
        // S^T = K * Q (Q pre-scaled by 0.125*log2e)
        f32x4 sc[4];
#pragma unroll
        for (int n = 0; n < 4; n++) {
            const short* kb = &Ks[cur][(16 * n + q) * 64];
            s16x8 kf0 = *(const s16x8*)(kb + ((g ^ sw) << 3));
            s16x8 kf1 = *(const s16x8*)(kb + (((g + 4) ^ sw) << 3));
            f32x4 z = {};
            z = __builtin_amdgcn_mfma_f32_16x16x32_bf16(kf0, qf0, z, 0, 0, 0);
            sc[n] = __builtin_amdgcn_mfma_f32_16x16x32_bf16(kf1, qf1, z, 0, 0, 0);
        }
        // online softmax, exp2 domain (per q row = lane&15)
        float tm = -INFINITY;
#pragma unroll
        for (int n = 0; n < 4; n++)
#pragma unroll
            for (int r = 0; r < 4; r++) tm = fmaxf(tm, sc[n][r]);
        tm = fmaxf(tm, __shfl_xor(tm, 16));
        tm = fmaxf(tm, __shfl_xor(tm, 32));
        if (!__all(tm <= mst + 8.f)) {   // defer-max
            float mnew = fmaxf(mst, tm);
            float alpha = exp2f(mst - mnew);
            lst *= alpha;
#pragma unroll
            for (int r = 0; r < 4; r++) {
                float ar = __shfl(alpha, 4 * g + r);
#pragma unroll
                for (int n = 0; n < 4; n++) accy[n][r] *= ar;
            }
            mst = mnew;
        }
        float p[4][4];
        float ps = 0.f;
#pragma unroll
        for (int n = 0; n < 4; n++)
#pragma unroll
            for (int r = 0; r < 4; r++) {
                p[n][r] = exp2f(sc[n][r] - mst);  // bounded by 2^8
                ps += p[n][r];
            }
        ps += __shfl_xor(ps, 16);
        ps += __shfl_xor(ps, 32);
        lst += ps;
        // P -> LDS via cvt_pk (chunk-XOR layout; wave-private, no barrier)
#pragma unroll
        for (int n = 0; n < 4; n++) {
            unsigned w0, w1;
            asm("v_cvt_pk_bf16_f32 %0, %1, %2" : "=v"(w0) : "v"(p[n][0]), "v"(p[n][1]));
            asm("v_cvt_pk_bf16_f32 %0, %1, %2" : "=v"(w1) : "v"(p[n][2]), "v"(p[n][3]));
            unsigned long long pw = (unsigned long long)w0 | ((unsigned long long)w1 << 32);
            *(unsigned long long*)&Pl[wave][q * 64 + (((4 * n + g) ^ s2) << 2)] = pw;
        }
        s16x8 pa0 = *(const s16x8*)&Pl[wave][q * 64 + (((2 * g) ^ s2) << 2)];
        s16x8 pa1 = *(const s16x8*)&Pl[wave][q * 64 + (((8 + 2 * g) ^ s2) << 2)];
        // PV: A = P, B = V^T rows d=16n+q
#pragma unroll
        for (int n = 0; n < 4; n++) {
            int d = 16 * n + q, vw = d & 7;
            const short* vb = &Vs[cur][d * 64];
            s16x8 v0 = *(const s16x8*)(vb + ((g ^ vw) << 3));
            s16x8 v1 = *(const s16x8*)(vb + (((g + 4) ^ vw) << 3));
            accy[n] = __builtin_amdgcn_mfma_f32_16x16x32_bf16(pa0, v0, accy[n], 0, 0, 0);
            accy[n] = __builtin_amdgcn_mfma_f32_16x16x32_bf16(pa1, v1, accy[n], 0, 0, 0);
        }
    }
    // write y
    short* yb = y + ((size_t)b * T + qt * 64 + wave * 16) * 1024 + h * 64;
#pragma unroll
    for (int r = 0; r < 4; r++) {
        float linv = 1.f / __shfl(lst, 4 * g + r);
#pragma unroll
        for (int n = 0; n < 4; n++)
            yb[(size_t)(4 * g + r) * 1024 + 16 * n + q] = f2bf(accy[n][r] * linv);
    }
}

extern "C" void kernel_launch(void* const* d_in, const int* in_sizes, int n_in,
                              void* d_out, int out_size, void* d_ws, size_t ws_size,
                              hipStream_t stream) {
    const float* x           = (const float*)d_in[0];
    const float* ln1_w       = (const float*)d_in[1];
    const float* ln1_b       = (const float*)d_in[2];
    const float* attn_w      = (const float*)d_in[3];
    const float* attn_b      = (const float*)d_in[4];
    const float* attn_proj_w = (const float*)d_in[5];
    const float* attn_proj_b = (const float*)d_in[6];
    const float* ln2_w       = (const float*)d_in[7];
    const float* ln2_b       = (const float*)d_in[8];
    const float* fc_w        = (const float*)d_in[9];
    const float* fc_b        = (const float*)d_in[10];
    const float* mlp_proj_w  = (const float*)d_in[11];
    const float* mlp_proj_b  = (const float*)d_in[12];

    const int M = 4096;  // B*T

    size_t off = 0;
    char* wsb = (char*)d_ws;
    auto alloc = [&](size_t bytes) {
        void* p = wsb + off;
        off += (bytes + 255) & ~(size_t)255;
        return p;
    };
    short* wt_attn  = (short*)alloc(3072ull * 1024 * 2);
    short* wt_proj  = (short*)alloc(1024ull * 1024 * 2);
    short* wt_fc    = (short*)alloc(4096ull * 1024 * 2);
    short* wt_mproj = (short*)alloc(1024ull * 4096 * 2);
    short* h1       = (short*)alloc((size_t)M * 1024 * 2);
    short* qkvb     = (short*)alloc((size_t)M * 3072 * 2);
    short* yb       = (short*)alloc((size_t)M * 1024 * 2);
    float* x1       = (float*)alloc((size_t)M * 1024 * 4);
    short* vtg      = (short*)alloc((size_t)M * 1024 * 2);   // V transposed [bh*64+d][T]
    short* h2       = qkvb;  // aliases qkv+y region (both dead by fc GEMM)

    transpose_cast<<<dim3(3072 / 32, 1024 / 32), 256, 0, stream>>>(attn_w, wt_attn, 1024, 3072);
    transpose_cast<<<dim3(1024 / 32, 1024 / 32), 256, 0, stream>>>(attn_proj_w, wt_proj, 1024, 1024);
    transpose_cast<<<dim3(4096 / 32, 1024 / 32), 256, 0, stream>>>(fc_w, wt_fc, 1024, 4096);
    transpose_cast<<<dim3(1024 / 32, 4096 / 32), 256, 0, stream>>>(mlp_proj_w, wt_mproj, 4096, 1024);

    ln_kernel<<<M, 256, 0, stream>>>(x, ln1_w, ln1_b, h1);
    gemm_bt<short, false, false, true><<<dim3(3072 / 128, M / 128), 256, 0, stream>>>(
        h1, wt_attn, attn_b, nullptr, qkvb, M, 3072, 1024);
    vtrans_kernel<<<dim3(2048 / 32, 64), 256, 0, stream>>>(qkvb, vtg);
    attn_kernel<<<1024, 256, 0, stream>>>(qkvb, vtg, yb);
    gemm_bt<float, false, true, false><<<dim3(1024 / 128, M / 128), 256, 0, stream>>>(
        yb, wt_proj, attn_proj_b, x, x1, M, 1024, 1024);
    ln_kernel<<<M, 256, 0, stream>>>(x1, ln2_w, ln2_b, h1);
    gemm_bt<short, true, false, false><<<dim3(4096 / 128, M / 128), 256, 0, stream>>>(
        h1, wt_fc, fc_b, nullptr, h2, M, 4096, 1024);
    gemm_bt<float, false, true, false><<<dim3(1024 / 128, M / 128), 256, 0, stream>>>(
        h2, wt_mproj, mlp_proj_b, x1, (float*)d_out, M, 1024, 4096);
}

// Round 5
// 315.547 us; speedup vs baseline: 1.3049x; 1.0337x over previous
//
#include <hip/hip_runtime.h>

typedef __attribute__((ext_vector_type(4))) float  f32x4;
typedef __attribute__((ext_vector_type(8))) short  s16x8;
typedef __attribute__((ext_vector_type(4))) short  s16x4;

__device__ __forceinline__ short f2bf(float f) {
    unsigned u = __builtin_bit_cast(unsigned, f);
    u += 0x7fff + ((u >> 16) & 1);
    return (short)(u >> 16);
}

__device__ __forceinline__ void load_lds16(const void* g, void* l) {
    __builtin_amdgcn_global_load_lds(
        (const __attribute__((address_space(1))) unsigned int*)g,
        (__attribute__((address_space(3))) unsigned int*)l, 16, 0, 0);
}

// ---------------- transpose + cast: W[K][N] f32 -> Wt[N][K] bf16 ----------------
__global__ __launch_bounds__(256) void transpose_cast(const float* __restrict__ W,
                                                      short* __restrict__ Wt,
                                                      int K, int N) {
    __shared__ float t[32][33];
    int n0 = blockIdx.x * 32, k0 = blockIdx.y * 32;
    int tx = threadIdx.x & 31, ty = threadIdx.x >> 5;  // 32 x 8
#pragma unroll
    for (int i = 0; i < 4; i++)
        t[ty + 8 * i][tx] = W[(size_t)(k0 + ty + 8 * i) * N + n0 + tx];
    __syncthreads();
#pragma unroll
    for (int i = 0; i < 4; i++)
        Wt[(size_t)(n0 + ty + 8 * i) * K + k0 + tx] = f2bf(t[tx][ty + 8 * i]);
}

// ---------------- V transpose: qkv V-part -> Vtg [(b*16+h)*64+d][token] ----------------
__global__ __launch_bounds__(256) void vtrans_kernel(const short* __restrict__ qkv,
                                                     short* __restrict__ Vtg) {
    const int T = 2048, C3 = 3072;
    __shared__ short tl[32][33];
    int bh = blockIdx.y >> 1;
    int b = bh >> 4, h = bh & 15;
    int dh = (blockIdx.y & 1) * 32;
    int t0 = blockIdx.x * 32;
    int tx = threadIdx.x & 31, ty = threadIdx.x >> 5;
    const short* src = qkv + (size_t)b * T * C3 + 2048 + h * 64 + dh;
#pragma unroll
    for (int i = 0; i < 4; i++)
        tl[ty + 8 * i][tx] = src[(size_t)(t0 + ty + 8 * i) * C3 + tx];
    __syncthreads();
#pragma unroll
    for (int i = 0; i < 4; i++)
        Vtg[((size_t)bh * 64 + dh + ty + 8 * i) * T + t0 + tx] = tl[tx][ty + 8 * i];
}

// ---------------- LayerNorm: f32 [rows][1024] -> bf16 ----------------
__global__ __launch_bounds__(256) void ln_kernel(const float* __restrict__ x,
                                                 const float* __restrict__ w,
                                                 const float* __restrict__ b,
                                                 short* __restrict__ out) {
    int row = blockIdx.x;
    int tid = threadIdx.x;
    const float4 v = ((const float4*)(x + (size_t)row * 1024))[tid];
    float s  = v.x + v.y + v.z + v.w;
    float ss = v.x * v.x + v.y * v.y + v.z * v.z + v.w * v.w;
#pragma unroll
    for (int o = 32; o > 0; o >>= 1) {
        s  += __shfl_down(s, o);
        ss += __shfl_down(ss, o);
    }
    __shared__ float rs[4], rq[4];
    int wave = tid >> 6, lane = tid & 63;
    if (lane == 0) { rs[wave] = s; rq[wave] = ss; }
    __syncthreads();
    float tot = rs[0] + rs[1] + rs[2] + rs[3];
    float tq  = rq[0] + rq[1] + rq[2] + rq[3];
    float mu   = tot * (1.f / 1024.f);
    float var  = tq * (1.f / 1024.f) - mu * mu;
    float rstd = rsqrtf(var + 1e-5f);
    const float4 wv = ((const float4*)w)[tid];
    const float4 bv = ((const float4*)b)[tid];
    s16x4 o;
    o[0] = f2bf((v.x - mu) * rstd * wv.x + bv.x);
    o[1] = f2bf((v.y - mu) * rstd * wv.y + bv.y);
    o[2] = f2bf((v.z - mu) * rstd * wv.z + bv.z);
    o[3] = f2bf((v.w - mu) * rstd * wv.w + bv.w);
    ((s16x4*)(out + (size_t)row * 1024))[tid] = o;
}

// ---------------- GEMM: C[M][N] = A * Bt^T + bias (+res) (gelu?) ----------------
template <typename OUT_T, bool GELU, bool RES, bool SCALE_Q>
__global__ __launch_bounds__(256) void gemm_bt(const short* __restrict__ A,
                                               const short* __restrict__ Bt,
                                               const float* __restrict__ bias,
                                               const float* __restrict__ res,
                                               OUT_T* __restrict__ C,
                                               int M, int N, int K) {
    __shared__ __align__(16) short As[128 * 32];
    __shared__ __align__(16) short Bs[128 * 32];
    int tid = threadIdx.x;
    int m0 = blockIdx.y * 128, n0 = blockIdx.x * 128;
    int wave = tid >> 6, lane = tid & 63;
    int wr = wave >> 1, wc = wave & 1;
    int g = lane >> 4, q = lane & 15;
    f32x4 acc[4][4] = {};
    const short* Ab = A + (size_t)m0 * K;
    const short* Bb = Bt + (size_t)n0 * K;
    int srow = tid >> 2;
    int scol = (tid & 3) * 8;
    for (int k0 = 0; k0 < K; k0 += 32) {
        __syncthreads();
        load_lds16(Ab + (size_t)srow * K + k0 + scol, As + tid * 8);
        load_lds16(Ab + (size_t)(srow + 64) * K + k0 + scol, As + 2048 + tid * 8);
        load_lds16(Bb + (size_t)srow * K + k0 + scol, Bs + tid * 8);
        load_lds16(Bb + (size_t)(srow + 64) * K + k0 + scol, Bs + 2048 + tid * 8);
        __syncthreads();
        s16x8 a[4], bf[4];
#pragma unroll
        for (int mi = 0; mi < 4; mi++)
            a[mi] = *(const s16x8*)(As + (wr * 64 + mi * 16 + q) * 32 + g * 8);
#pragma unroll
        for (int ni = 0; ni < 4; ni++)
            bf[ni] = *(const s16x8*)(Bs + (wc * 64 + ni * 16 + q) * 32 + g * 8);
#pragma unroll
        for (int mi = 0; mi < 4; mi++)
#pragma unroll
            for (int ni = 0; ni < 4; ni++)
                acc[mi][ni] = __builtin_amdgcn_mfma_f32_16x16x32_bf16(a[mi], bf[ni], acc[mi][ni], 0, 0, 0);
    }
#pragma unroll
    for (int mi = 0; mi < 4; mi++) {
#pragma unroll
        for (int ni = 0; ni < 4; ni++) {
            int row = m0 + wr * 64 + mi * 16 + g * 4;
            int col = n0 + wc * 64 + ni * 16 + q;
            float bb = bias[col];
#pragma unroll
            for (int r = 0; r < 4; r++) {
                float v = acc[mi][ni][r] + bb;
                if (RES) v += res[(size_t)(row + r) * N + col];
                if (GELU) {
                    float aa = 0.7978845608028654f * (v + 0.044715f * v * v * v);
                    float th = 1.f - 2.f / (__expf(2.f * aa) + 1.f);
                    v = 0.5f * v * (1.f + th);
                }
                if (SCALE_Q && col < 1024) v *= 0.18033688011112042f;  // 0.125*log2(e)
                if constexpr (sizeof(OUT_T) == 2)
                    C[(size_t)(row + r) * N + col] = f2bf(v);
                else
                    C[(size_t)(row + r) * N + col] = v;
            }
        }
    }
}

// ---------------- split-K GEMM: partials[kz][M][N] += A[:, kz*Klen:(kz+1)*Klen] * Bt^T ----------------
__global__ __launch_bounds__(256) void gemm_bt_sk(const short* __restrict__ A,
                                                  const short* __restrict__ Bt,
                                                  float* __restrict__ part,
                                                  int M, int N, int K, int Klen) {
    __shared__ __align__(16) short As[128 * 32];
    __shared__ __align__(16) short Bs[128 * 32];
    int tid = threadIdx.x;
    int m0 = blockIdx.y * 128, n0 = blockIdx.x * 128;
    int kz = blockIdx.z;
    int wave = tid >> 6, lane = tid & 63;
    int wr = wave >> 1, wc = wave & 1;
    int g = lane >> 4, q = lane & 15;
    f32x4 acc[4][4] = {};
    const short* Ab = A + (size_t)m0 * K;
    const short* Bb = Bt + (size_t)n0 * K;
    int srow = tid >> 2;
    int scol = (tid & 3) * 8;
    int kend = kz * Klen + Klen;
    for (int k0 = kz * Klen; k0 < kend; k0 += 32) {
        __syncthreads();
        load_lds16(Ab + (size_t)srow * K + k0 + scol, As + tid * 8);
        load_lds16(Ab + (size_t)(srow + 64) * K + k0 + scol, As + 2048 + tid * 8);
        load_lds16(Bb + (size_t)srow * K + k0 + scol, Bs + tid * 8);
        load_lds16(Bb + (size_t)(srow + 64) * K + k0 + scol, Bs + 2048 + tid * 8);
        __syncthreads();
        s16x8 a[4], bf[4];
#pragma unroll
        for (int mi = 0; mi < 4; mi++)
            a[mi] = *(const s16x8*)(As + (wr * 64 + mi * 16 + q) * 32 + g * 8);
#pragma unroll
        for (int ni = 0; ni < 4; ni++)
            bf[ni] = *(const s16x8*)(Bs + (wc * 64 + ni * 16 + q) * 32 + g * 8);
#pragma unroll
        for (int mi = 0; mi < 4; mi++)
#pragma unroll
            for (int ni = 0; ni < 4; ni++)
                acc[mi][ni] = __builtin_amdgcn_mfma_f32_16x16x32_bf16(a[mi], bf[ni], acc[mi][ni], 0, 0, 0);
    }
    float* pb = part + (size_t)kz * M * N;
#pragma unroll
    for (int mi = 0; mi < 4; mi++) {
#pragma unroll
        for (int ni = 0; ni < 4; ni++) {
            int row = m0 + wr * 64 + mi * 16 + g * 4;
            int col = n0 + wc * 64 + ni * 16 + q;
#pragma unroll
            for (int r = 0; r < 4; r++)
                pb[(size_t)(row + r) * N + col] = acc[mi][ni][r];
        }
    }
}

// ---------------- reduce: out = sum_k part[k] + bias + res (all f32, vectorized) ----------------
template <int SK>
__global__ __launch_bounds__(256) void reduce_sk(const float* __restrict__ part,
                                                 const float* __restrict__ bias,
                                                 const float* __restrict__ res,
                                                 float* __restrict__ out,
                                                 int MN, int N) {
    int tot = MN >> 2;
    int nb4 = (N >> 2) - 1;  // N power of 2
    for (int i = blockIdx.x * 256 + threadIdx.x; i < tot; i += gridDim.x * 256) {
        float4 s = ((const float4*)part)[i];
#pragma unroll
        for (int k = 1; k < SK; k++) {
            float4 p = ((const float4*)(part + (size_t)k * MN))[i];
            s.x += p.x; s.y += p.y; s.z += p.z; s.w += p.w;
        }
        float4 bv = ((const float4*)bias)[i & nb4];
        float4 rv = ((const float4*)res)[i];
        float4 o;
        o.x = s.x + bv.x + rv.x;
        o.y = s.y + bv.y + rv.y;
        o.z = s.z + bv.z + rv.z;
        o.w = s.w + bv.w + rv.w;
        ((float4*)out)[i] = o;
    }
}

// ---------------- Flash attention v3 ----------------
__global__ __launch_bounds__(256) void attn_kernel(const short* __restrict__ qkv,
                                                   const short* __restrict__ Vtg,
                                                   short* __restrict__ y) {
    const int T = 2048, C3 = 3072;
    int wg = blockIdx.x;
    int mapped = (wg & 7) * 128 + (wg >> 3);   // XCD gets contiguous chunk: 4 heads/XCD
    int bh = mapped >> 5, qt = mapped & 31;
    int b = bh >> 4, h = bh & 15;
    int tid = threadIdx.x, lane = tid & 63, wave = tid >> 6;
    int g = lane >> 4, q = lane & 15;
    const short* base = qkv + (size_t)b * T * C3;

    int qrow = qt * 64 + wave * 16 + q;
    const short* qp = base + (size_t)qrow * C3 + h * 64 + g * 8;
    s16x8 qf0 = *(const s16x8*)qp;
    s16x8 qf1 = *(const s16x8*)(qp + 32);

    __shared__ __align__(16) short Ks[2][64 * 64];
    __shared__ __align__(16) short Vs[2][64 * 64];
    __shared__ __align__(16) short Pl[4][16 * 64];

    int srow = tid >> 3, sc8 = tid & 7;
    const short* ksrc = base + 1024 + h * 64 + (size_t)srow * C3 + ((sc8 ^ (srow & 7)) << 3);
    const short* vsrc = Vtg + ((size_t)bh * 64 + srow) * T + ((sc8 ^ (srow & 7)) << 3);

    auto stage = [&](int bi, int t) {
        const short* kp = ksrc + (size_t)(t * 64) * C3;
        load_lds16(kp, &Ks[bi][tid * 8]);
        load_lds16(kp + (size_t)32 * C3, &Ks[bi][tid * 8 + 2048]);
        const short* vp = vsrc + t * 64;
        load_lds16(vp, &Vs[bi][tid * 8]);
        load_lds16(vp + (size_t)32 * T, &Vs[bi][tid * 8 + 2048]);
    };

    float mst = -INFINITY, lst = 0.f;
    f32x4 accy[4] = {};
    int sw = q & 7;
    int s2 = sw << 1;

    stage(0, 0);
    for (int t = 0; t < 32; ++t) {
        int cur = t & 1;
        __syncthreads();
        if (t < 31) stage(cur ^ 1, t + 1);
        f32x4 sc[4];
#pragma unroll
        for (int n = 0; n < 4; n++) {
            const short* kb = &Ks[cur][(16 * n + q) * 64];
            s16x8 kf0 = *(const s16x8*)(kb + ((g ^ sw) << 3));
            s16x8 kf1 = *(const s16x8*)(kb + (((g + 4) ^ sw) << 3));
            f32x4 z = {};
            z = __builtin_amdgcn_mfma_f32_16x16x32_bf16(kf0, qf0, z, 0, 0, 0);
            sc[n] = __builtin_amdgcn_mfma_f32_16x16x32_bf16(kf1, qf1, z, 0, 0, 0);
        }
        float tm = -INFINITY;
#pragma unroll
        for (int n = 0; n < 4; n++)
#pragma unroll
            for (int r = 0; r < 4; r++) tm = fmaxf(tm, sc[n][r]);
        tm = fmaxf(tm, __shfl_xor(tm, 16));
        tm = fmaxf(tm, __shfl_xor(tm, 32));
        if (!__all(tm <= mst + 8.f)) {
            float mnew = fmaxf(mst, tm);
            float alpha = exp2f(mst - mnew);
            lst *= alpha;
#pragma unroll
            for (int r = 0; r < 4; r++) {
                float ar = __shfl(alpha, 4 * g + r);
#pragma unroll
                for (int n = 0; n < 4; n++) accy[n][r] *= ar;
            }
            mst = mnew;
        }
        float p[4][4];
        float ps = 0.f;
#pragma unroll
        for (int n = 0; n < 4; n++)
#pragma unroll
            for (int r = 0; r < 4; r++) {
                p[n][r] = exp2f(sc[n][r] - mst);
                ps += p[n][r];
            }
        ps += __shfl_xor(ps, 16);
        ps += __shfl_xor(ps, 32);
        lst += ps;
#pragma unroll
        for (int n = 0; n < 4; n++) {
            unsigned w0, w1;
            asm("v_cvt_pk_bf16_f32 %0, %1, %2" : "=v"(w0) : "v"(p[n][0]), "v"(p[n][1]));
            asm("v_cvt_pk_bf16_f32 %0, %1, %2" : "=v"(w1) : "v"(p[n][2]), "v"(p[n][3]));
            unsigned long long pw = (unsigned long long)w0 | ((unsigned long long)w1 << 32);
            *(unsigned long long*)&Pl[wave][q * 64 + (((4 * n + g) ^ s2) << 2)] = pw;
        }
        s16x8 pa0 = *(const s16x8*)&Pl[wave][q * 64 + (((2 * g) ^ s2) << 2)];
        s16x8 pa1 = *(const s16x8*)&Pl[wave][q * 64 + (((8 + 2 * g) ^ s2) << 2)];
#pragma unroll
        for (int n = 0; n < 4; n++) {
            int d = 16 * n + q, vw = d & 7;
            const short* vb = &Vs[cur][d * 64];
            s16x8 v0 = *(const s16x8*)(vb + ((g ^ vw) << 3));
            s16x8 v1 = *(const s16x8*)(vb + (((g + 4) ^ vw) << 3));
            accy[n] = __builtin_amdgcn_mfma_f32_16x16x32_bf16(pa0, v0, accy[n], 0, 0, 0);
            accy[n] = __builtin_amdgcn_mfma_f32_16x16x32_bf16(pa1, v1, accy[n], 0, 0, 0);
        }
    }
    short* yb = y + ((size_t)b * T + qt * 64 + wave * 16) * 1024 + h * 64;
#pragma unroll
    for (int r = 0; r < 4; r++) {
        float linv = 1.f / __shfl(lst, 4 * g + r);
#pragma unroll
        for (int n = 0; n < 4; n++)
            yb[(size_t)(4 * g + r) * 1024 + 16 * n + q] = f2bf(accy[n][r] * linv);
    }
}

extern "C" void kernel_launch(void* const* d_in, const int* in_sizes, int n_in,
                              void* d_out, int out_size, void* d_ws, size_t ws_size,
                              hipStream_t stream) {
    const float* x           = (const float*)d_in[0];
    const float* ln1_w       = (const float*)d_in[1];
    const float* ln1_b       = (const float*)d_in[2];
    const float* attn_w      = (const float*)d_in[3];
    const float* attn_b      = (const float*)d_in[4];
    const float* attn_proj_w = (const float*)d_in[5];
    const float* attn_proj_b = (const float*)d_in[6];
    const float* ln2_w       = (const float*)d_in[7];
    const float* ln2_b       = (const float*)d_in[8];
    const float* fc_w        = (const float*)d_in[9];
    const float* fc_b        = (const float*)d_in[10];
    const float* mlp_proj_w  = (const float*)d_in[11];
    const float* mlp_proj_b  = (const float*)d_in[12];

    const int M = 4096;  // B*T

    size_t off = 0;
    char* wsb = (char*)d_ws;
    auto alloc = [&](size_t bytes) {
        void* p = wsb + off;
        off += (bytes + 255) & ~(size_t)255;
        return p;
    };
    short* wt_attn  = (short*)alloc(3072ull * 1024 * 2);
    short* wt_proj  = (short*)alloc(1024ull * 1024 * 2);
    short* wt_fc    = (short*)alloc(4096ull * 1024 * 2);
    short* wt_mproj = (short*)alloc(1024ull * 4096 * 2);
    short* h1       = (short*)alloc((size_t)M * 1024 * 2);
    short* qkvb     = (short*)alloc((size_t)M * 3072 * 2);
    short* yb       = (short*)alloc((size_t)M * 1024 * 2);
    float* x1       = (float*)alloc((size_t)M * 1024 * 4);
    short* vtg      = (short*)alloc((size_t)M * 1024 * 2);   // V transposed
    short* h2       = qkvb;  // aliases qkv+y region (both dead by fc GEMM)

    // split-K partials for mlp_proj (fp32, [SK][M][1024]); SK chosen by ws capacity.
    size_t base_off = off;
    int SK = 0;
    if (ws_size >= base_off + 4ull * M * 1024 * 4) SK = 4;
    else if (ws_size >= base_off + 2ull * M * 1024 * 4) SK = 2;
    float* part = (float*)(wsb + base_off);

    transpose_cast<<<dim3(3072 / 32, 1024 / 32), 256, 0, stream>>>(attn_w, wt_attn, 1024, 3072);
    transpose_cast<<<dim3(1024 / 32, 1024 / 32), 256, 0, stream>>>(attn_proj_w, wt_proj, 1024, 1024);
    transpose_cast<<<dim3(4096 / 32, 1024 / 32), 256, 0, stream>>>(fc_w, wt_fc, 1024, 4096);
    transpose_cast<<<dim3(1024 / 32, 4096 / 32), 256, 0, stream>>>(mlp_proj_w, wt_mproj, 4096, 1024);

    ln_kernel<<<M, 256, 0, stream>>>(x, ln1_w, ln1_b, h1);
    gemm_bt<short, false, false, true><<<dim3(3072 / 128, M / 128), 256, 0, stream>>>(
        h1, wt_attn, attn_b, nullptr, qkvb, M, 3072, 1024);
    vtrans_kernel<<<dim3(2048 / 32, 64), 256, 0, stream>>>(qkvb, vtg);
    attn_kernel<<<1024, 256, 0, stream>>>(qkvb, vtg, yb);
    gemm_bt<float, false, true, false><<<dim3(1024 / 128, M / 128), 256, 0, stream>>>(
        yb, wt_proj, attn_proj_b, x, x1, M, 1024, 1024);
    ln_kernel<<<M, 256, 0, stream>>>(x1, ln2_w, ln2_b, h1);
    gemm_bt<short, true, false, false><<<dim3(4096 / 128, M / 128), 256, 0, stream>>>(
        h1, wt_fc, fc_b, nullptr, h2, M, 4096, 1024);

    // out = x1 + h2 @ mlp_proj_w + mlp_proj_b  (split-K when ws allows)
    if (SK == 4) {
        gemm_bt_sk<<<dim3(1024 / 128, M / 128, 4), 256, 0, stream>>>(
            h2, wt_mproj, part, M, 1024, 4096, 1024);
        reduce_sk<4><<<2048, 256, 0, stream>>>(part, mlp_proj_b, x1, (float*)d_out, M * 1024, 1024);
    } else if (SK == 2) {
        gemm_bt_sk<<<dim3(1024 / 128, M / 128, 2), 256, 0, stream>>>(
            h2, wt_mproj, part, M, 1024, 4096, 2048);
        reduce_sk<2><<<2048, 256, 0, stream>>>(part, mlp_proj_b, x1, (float*)d_out, M * 1024, 1024);
    } else {
        gemm_bt<float, false, true, false><<<dim3(1024 / 128, M / 128), 256, 0, stream>>>(
            h2, wt_mproj, mlp_proj_b, x1, (float*)d_out, M, 1024, 4096);
    }
}

// Round 6
// 308.376 us; speedup vs baseline: 1.3353x; 1.0233x over previous
//
#include <hip/hip_runtime.h>

typedef __attribute__((ext_vector_type(4)))  float  f32x4;
typedef __attribute__((ext_vector_type(16))) float  f32x16;
typedef __attribute__((ext_vector_type(8)))  short  s16x8;
typedef __attribute__((ext_vector_type(4)))  short  s16x4;
typedef __attribute__((ext_vector_type(4)))  unsigned u32x4;
typedef __attribute__((ext_vector_type(2)))  unsigned u32x2;
typedef __attribute__((ext_vector_type(2)))  int    i32x2;

__device__ __forceinline__ short f2bf(float f) {
    unsigned u = __builtin_bit_cast(unsigned, f);
    u += 0x7fff + ((u >> 16) & 1);
    return (short)(u >> 16);
}

__device__ __forceinline__ void load_lds16(const void* g, void* l) {
    __builtin_amdgcn_global_load_lds(
        (const __attribute__((address_space(1))) unsigned int*)g,
        (__attribute__((address_space(3))) unsigned int*)l, 16, 0, 0);
}

// ---------------- transpose + cast: W[K][N] f32 -> Wt[N][K] bf16 ----------------
__global__ __launch_bounds__(256) void transpose_cast(const float* __restrict__ W,
                                                      short* __restrict__ Wt,
                                                      int K, int N) {
    __shared__ float t[32][33];
    int n0 = blockIdx.x * 32, k0 = blockIdx.y * 32;
    int tx = threadIdx.x & 31, ty = threadIdx.x >> 5;  // 32 x 8
#pragma unroll
    for (int i = 0; i < 4; i++)
        t[ty + 8 * i][tx] = W[(size_t)(k0 + ty + 8 * i) * N + n0 + tx];
    __syncthreads();
#pragma unroll
    for (int i = 0; i < 4; i++)
        Wt[(size_t)(n0 + ty + 8 * i) * K + k0 + tx] = f2bf(t[tx][ty + 8 * i]);
}

// ---------------- V transpose: qkv V-part -> Vtg [(b*16+h)*64+d][token] ----------------
__global__ __launch_bounds__(256) void vtrans_kernel(const short* __restrict__ qkv,
                                                     short* __restrict__ Vtg) {
    const int T = 2048, C3 = 3072;
    __shared__ short tl[32][33];
    int bh = blockIdx.y >> 1;
    int b = bh >> 4, h = bh & 15;
    int dh = (blockIdx.y & 1) * 32;
    int t0 = blockIdx.x * 32;
    int tx = threadIdx.x & 31, ty = threadIdx.x >> 5;
    const short* src = qkv + (size_t)b * T * C3 + 2048 + h * 64 + dh;
#pragma unroll
    for (int i = 0; i < 4; i++)
        tl[ty + 8 * i][tx] = src[(size_t)(t0 + ty + 8 * i) * C3 + tx];
    __syncthreads();
#pragma unroll
    for (int i = 0; i < 4; i++)
        Vtg[((size_t)bh * 64 + dh + ty + 8 * i) * T + t0 + tx] = tl[tx][ty + 8 * i];
}

// ---------------- LayerNorm: f32 [rows][1024] -> bf16 ----------------
__global__ __launch_bounds__(256) void ln_kernel(const float* __restrict__ x,
                                                 const float* __restrict__ w,
                                                 const float* __restrict__ b,
                                                 short* __restrict__ out) {
    int row = blockIdx.x;
    int tid = threadIdx.x;
    const float4 v = ((const float4*)(x + (size_t)row * 1024))[tid];
    float s  = v.x + v.y + v.z + v.w;
    float ss = v.x * v.x + v.y * v.y + v.z * v.z + v.w * v.w;
#pragma unroll
    for (int o = 32; o > 0; o >>= 1) {
        s  += __shfl_down(s, o);
        ss += __shfl_down(ss, o);
    }
    __shared__ float rs[4], rq[4];
    int wave = tid >> 6, lane = tid & 63;
    if (lane == 0) { rs[wave] = s; rq[wave] = ss; }
    __syncthreads();
    float tot = rs[0] + rs[1] + rs[2] + rs[3];
    float tq  = rq[0] + rq[1] + rq[2] + rq[3];
    float mu   = tot * (1.f / 1024.f);
    float var  = tq * (1.f / 1024.f) - mu * mu;
    float rstd = rsqrtf(var + 1e-5f);
    const float4 wv = ((const float4*)w)[tid];
    const float4 bv = ((const float4*)b)[tid];
    s16x4 o;
    o[0] = f2bf((v.x - mu) * rstd * wv.x + bv.x);
    o[1] = f2bf((v.y - mu) * rstd * wv.y + bv.y);
    o[2] = f2bf((v.z - mu) * rstd * wv.z + bv.z);
    o[3] = f2bf((v.w - mu) * rstd * wv.w + bv.w);
    ((s16x4*)(out + (size_t)row * 1024))[tid] = o;
}

// ---------------- GEMM: C[M][N] = A * Bt^T + bias (+res) (gelu?) ----------------
template <typename OUT_T, bool GELU, bool RES, bool SCALE_Q>
__global__ __launch_bounds__(256) void gemm_bt(const short* __restrict__ A,
                                               const short* __restrict__ Bt,
                                               const float* __restrict__ bias,
                                               const float* __restrict__ res,
                                               OUT_T* __restrict__ C,
                                               int M, int N, int K) {
    __shared__ __align__(16) short As[128 * 32];
    __shared__ __align__(16) short Bs[128 * 32];
    int tid = threadIdx.x;
    int m0 = blockIdx.y * 128, n0 = blockIdx.x * 128;
    int wave = tid >> 6, lane = tid & 63;
    int wr = wave >> 1, wc = wave & 1;
    int g = lane >> 4, q = lane & 15;
    f32x4 acc[4][4] = {};
    const short* Ab = A + (size_t)m0 * K;
    const short* Bb = Bt + (size_t)n0 * K;
    int srow = tid >> 2;
    int scol = (tid & 3) * 8;
    for (int k0 = 0; k0 < K; k0 += 32) {
        __syncthreads();
        load_lds16(Ab + (size_t)srow * K + k0 + scol, As + tid * 8);
        load_lds16(Ab + (size_t)(srow + 64) * K + k0 + scol, As + 2048 + tid * 8);
        load_lds16(Bb + (size_t)srow * K + k0 + scol, Bs + tid * 8);
        load_lds16(Bb + (size_t)(srow + 64) * K + k0 + scol, Bs + 2048 + tid * 8);
        __syncthreads();
        s16x8 a[4], bf[4];
#pragma unroll
        for (int mi = 0; mi < 4; mi++)
            a[mi] = *(const s16x8*)(As + (wr * 64 + mi * 16 + q) * 32 + g * 8);
#pragma unroll
        for (int ni = 0; ni < 4; ni++)
            bf[ni] = *(const s16x8*)(Bs + (wc * 64 + ni * 16 + q) * 32 + g * 8);
#pragma unroll
        for (int mi = 0; mi < 4; mi++)
#pragma unroll
            for (int ni = 0; ni < 4; ni++)
                acc[mi][ni] = __builtin_amdgcn_mfma_f32_16x16x32_bf16(a[mi], bf[ni], acc[mi][ni], 0, 0, 0);
    }
#pragma unroll
    for (int mi = 0; mi < 4; mi++) {
#pragma unroll
        for (int ni = 0; ni < 4; ni++) {
            int row = m0 + wr * 64 + mi * 16 + g * 4;
            int col = n0 + wc * 64 + ni * 16 + q;
            float bb = bias[col];
#pragma unroll
            for (int r = 0; r < 4; r++) {
                float v = acc[mi][ni][r] + bb;
                if (RES) v += res[(size_t)(row + r) * N + col];
                if (GELU) {
                    float aa = 0.7978845608028654f * (v + 0.044715f * v * v * v);
                    float th = 1.f - 2.f / (__expf(2.f * aa) + 1.f);
                    v = 0.5f * v * (1.f + th);
                }
                if (SCALE_Q && col < 1024) v *= 0.18033688011112042f;  // 0.125*log2(e)
                if constexpr (sizeof(OUT_T) == 2)
                    C[(size_t)(row + r) * N + col] = f2bf(v);
                else
                    C[(size_t)(row + r) * N + col] = v;
            }
        }
    }
}

// ---------------- split-K GEMM ----------------
__global__ __launch_bounds__(256) void gemm_bt_sk(const short* __restrict__ A,
                                                  const short* __restrict__ Bt,
                                                  float* __restrict__ part,
                                                  int M, int N, int K, int Klen) {
    __shared__ __align__(16) short As[128 * 32];
    __shared__ __align__(16) short Bs[128 * 32];
    int tid = threadIdx.x;
    int m0 = blockIdx.y * 128, n0 = blockIdx.x * 128;
    int kz = blockIdx.z;
    int wave = tid >> 6, lane = tid & 63;
    int wr = wave >> 1, wc = wave & 1;
    int g = lane >> 4, q = lane & 15;
    f32x4 acc[4][4] = {};
    const short* Ab = A + (size_t)m0 * K;
    const short* Bb = Bt + (size_t)n0 * K;
    int srow = tid >> 2;
    int scol = (tid & 3) * 8;
    int kend = kz * Klen + Klen;
    for (int k0 = kz * Klen; k0 < kend; k0 += 32) {
        __syncthreads();
        load_lds16(Ab + (size_t)srow * K + k0 + scol, As + tid * 8);
        load_lds16(Ab + (size_t)(srow + 64) * K + k0 + scol, As + 2048 + tid * 8);
        load_lds16(Bb + (size_t)srow * K + k0 + scol, Bs + tid * 8);
        load_lds16(Bb + (size_t)(srow + 64) * K + k0 + scol, Bs + 2048 + tid * 8);
        __syncthreads();
        s16x8 a[4], bf[4];
#pragma unroll
        for (int mi = 0; mi < 4; mi++)
            a[mi] = *(const s16x8*)(As + (wr * 64 + mi * 16 + q) * 32 + g * 8);
#pragma unroll
        for (int ni = 0; ni < 4; ni++)
            bf[ni] = *(const s16x8*)(Bs + (wc * 64 + ni * 16 + q) * 32 + g * 8);
#pragma unroll
        for (int mi = 0; mi < 4; mi++)
#pragma unroll
            for (int ni = 0; ni < 4; ni++)
                acc[mi][ni] = __builtin_amdgcn_mfma_f32_16x16x32_bf16(a[mi], bf[ni], acc[mi][ni], 0, 0, 0);
    }
    float* pb = part + (size_t)kz * M * N;
#pragma unroll
    for (int mi = 0; mi < 4; mi++) {
#pragma unroll
        for (int ni = 0; ni < 4; ni++) {
            int row = m0 + wr * 64 + mi * 16 + g * 4;
            int col = n0 + wc * 64 + ni * 16 + q;
#pragma unroll
            for (int r = 0; r < 4; r++)
                pb[(size_t)(row + r) * N + col] = acc[mi][ni][r];
        }
    }
}

// ---------------- reduce: out = sum_k part[k] + bias + res ----------------
template <int SK>
__global__ __launch_bounds__(256) void reduce_sk(const float* __restrict__ part,
                                                 const float* __restrict__ bias,
                                                 const float* __restrict__ res,
                                                 float* __restrict__ out,
                                                 int MN, int N) {
    int tot = MN >> 2;
    int nb4 = (N >> 2) - 1;
    for (int i = blockIdx.x * 256 + threadIdx.x; i < tot; i += gridDim.x * 256) {
        float4 s = ((const float4*)part)[i];
#pragma unroll
        for (int k = 1; k < SK; k++) {
            float4 p = ((const float4*)(part + (size_t)k * MN))[i];
            s.x += p.x; s.y += p.y; s.z += p.z; s.w += p.w;
        }
        float4 bv = ((const float4*)bias)[i & nb4];
        float4 rv = ((const float4*)res)[i];
        float4 o;
        o.x = s.x + bv.x + rv.x;
        o.y = s.y + bv.y + rv.y;
        o.z = s.z + bv.z + rv.z;
        o.w = s.w + bv.w + rv.w;
        ((float4*)out)[i] = o;
    }
}

// ---------------- Flash attention v4: 32x32 MFMA, in-register softmax ----------------
// grid 512 (XCD-swizzled), 4 waves x 32 q rows = 128 q/block; KV tile 64, double-buffered.
// Swapped QK^T (mfma(K,Q)): lane owns q = lane&31 in BOTH halves -> softmax state
// needs only one shfl_xor(32) per reduce; alpha/norm are shuffle-free.
// P stays in registers: cvt_pk + permlane32_swap assemble PV B-fragments (T12).
__global__ __launch_bounds__(256) void attn_kernel(const short* __restrict__ qkv,
                                                   const short* __restrict__ Vtg,
                                                   short* __restrict__ y) {
    const int T = 2048, C3 = 3072;
    int wg = blockIdx.x;
    int mapped = (wg & 7) * 64 + (wg >> 3);   // 4 heads per XCD
    int bh = mapped >> 4, qt = mapped & 15;
    int b = bh >> 4, h = bh & 15;
    int tid = threadIdx.x, lane = tid & 63, wave = tid >> 6;
    int ql = lane & 31, hi = lane >> 5;
    const short* base = qkv + (size_t)b * T * C3;

    int qrow = qt * 128 + wave * 32 + ql;
    const short* qp = base + (size_t)qrow * C3 + h * 64;
    s16x8 qf[4];
#pragma unroll
    for (int s = 0; s < 4; s++)
        qf[s] = *(const s16x8*)(qp + ((2 * s + hi) << 3));

    __shared__ __align__(16) short Ks[2][64 * 64];
    __shared__ __align__(16) short Vs[2][64 * 64];

    int srow = tid >> 3, sc8 = tid & 7;
    const short* ksrc = base + 1024 + h * 64 + (size_t)srow * C3 + ((sc8 ^ (srow & 7)) << 3);
    const short* vsrc = Vtg + ((size_t)bh * 64 + srow) * T + ((sc8 ^ (srow & 7)) << 3);

    auto stage = [&](int bi, int t) {
        const short* kp = ksrc + (size_t)(t * 64) * C3;
        load_lds16(kp, &Ks[bi][tid * 8]);
        load_lds16(kp + (size_t)32 * C3, &Ks[bi][tid * 8 + 2048]);
        const short* vp = vsrc + t * 64;
        load_lds16(vp, &Vs[bi][tid * 8]);
        load_lds16(vp + (size_t)32 * T, &Vs[bi][tid * 8 + 2048]);
    };

    float mst = -INFINITY, lst = 0.f;
    f32x16 accY0 = {}, accY1 = {};
    int swz = ql & 7;

    stage(0, 0);
    for (int t = 0; t < 32; ++t) {
        int cur = t & 1;
        __syncthreads();
        if (t < 31) stage(cur ^ 1, t + 1);
        // QK^T: S^T[key][q], key groups 0..31 (s0) and 32..63 (s1)
        f32x16 s0 = {}, s1 = {};
        const short* kb0 = &Ks[cur][ql * 64];
        const short* kb1 = &Ks[cur][(32 + ql) * 64];
        __builtin_amdgcn_s_setprio(1);
#pragma unroll
        for (int s = 0; s < 4; s++) {
            int c = ((2 * s + hi) ^ swz) << 3;
            s16x8 k0 = *(const s16x8*)(kb0 + c);
            s16x8 k1 = *(const s16x8*)(kb1 + c);
            s0 = __builtin_amdgcn_mfma_f32_32x32x16_bf16(k0, qf[s], s0, 0, 0, 0);
            s1 = __builtin_amdgcn_mfma_f32_32x32x16_bf16(k1, qf[s], s1, 0, 0, 0);
        }
        __builtin_amdgcn_s_setprio(0);
        // row max (lane-local; q identical across the two lane halves)
        float tm = fmaxf(s0[0], s0[1]);
#pragma unroll
        for (int r = 2; r < 16; r++) tm = fmaxf(tm, s0[r]);
#pragma unroll
        for (int r = 0; r < 16; r++) tm = fmaxf(tm, s1[r]);
        tm = fmaxf(tm, __shfl_xor(tm, 32));
        if (!__all(tm <= mst + 8.f)) {   // defer-max (THR=8, exp2 domain)
            float mnew = fmaxf(mst, tm);
            float alpha = exp2f(mst - mnew);
            lst *= alpha;
#pragma unroll
            for (int r = 0; r < 16; r++) { accY0[r] *= alpha; accY1[r] *= alpha; }
            mst = mnew;
        }
        float ps = 0.f;
#pragma unroll
        for (int r = 0; r < 16; r++) { s0[r] = exp2f(s0[r] - mst); ps += s0[r]; }
#pragma unroll
        for (int r = 0; r < 16; r++) { s1[r] = exp2f(s1[r] - mst); ps += s1[r]; }
        ps += __shfl_xor(ps, 32);
        lst += ps;
        // Build PV B-fragments in-register. Step s covers keys [16s,16s+16);
        // group G=s>>1 (s0/s1), tt=s&1. Reg r of group: key kk=(r&3)+8*(r>>2)+4*hi.
        // swap(A=W_hi,B=W_lo): A'=[partner W_lo | own W_hi], B'=[own W_lo | partner W_hi]
        // -> frag words = {B'0, B'1, A'0, A'1} gives P[q][16s+8*hi+j], j=0..7.
        s16x8 pb[4];
#pragma unroll
        for (int s = 0; s < 4; s++) {
            int tt = (s & 1) * 8;
            unsigned lo0, lo1, hi0, hi1;
            if (s < 2) {
                asm("v_cvt_pk_bf16_f32 %0, %1, %2" : "=v"(lo0) : "v"(s0[tt + 0]), "v"(s0[tt + 1]));
                asm("v_cvt_pk_bf16_f32 %0, %1, %2" : "=v"(lo1) : "v"(s0[tt + 2]), "v"(s0[tt + 3]));
                asm("v_cvt_pk_bf16_f32 %0, %1, %2" : "=v"(hi0) : "v"(s0[tt + 4]), "v"(s0[tt + 5]));
                asm("v_cvt_pk_bf16_f32 %0, %1, %2" : "=v"(hi1) : "v"(s0[tt + 6]), "v"(s0[tt + 7]));
            } else {
                asm("v_cvt_pk_bf16_f32 %0, %1, %2" : "=v"(lo0) : "v"(s1[tt + 0]), "v"(s1[tt + 1]));
                asm("v_cvt_pk_bf16_f32 %0, %1, %2" : "=v"(lo1) : "v"(s1[tt + 2]), "v"(s1[tt + 3]));
                asm("v_cvt_pk_bf16_f32 %0, %1, %2" : "=v"(hi0) : "v"(s1[tt + 4]), "v"(s1[tt + 5]));
                asm("v_cvt_pk_bf16_f32 %0, %1, %2" : "=v"(hi1) : "v"(s1[tt + 6]), "v"(s1[tt + 7]));
            }
            i32x2 r0 = __builtin_amdgcn_permlane32_swap((int)hi0, (int)lo0, false, false);
            i32x2 r1 = __builtin_amdgcn_permlane32_swap((int)hi1, (int)lo1, false, false);
            u32x4 w;
            w[0] = (unsigned)r0[1]; w[1] = (unsigned)r1[1];
            w[2] = (unsigned)r0[0]; w[3] = (unsigned)r1[0];
            pb[s] = __builtin_bit_cast(s16x8, w);
        }
        // PV: Y^T[d][q] += V^T[d][k] * P^T[k][q]; d-groups 0-31 (accY0), 32-63 (accY1)
        const short* vb0 = &Vs[cur][ql * 64];
        const short* vb1 = &Vs[cur][(32 + ql) * 64];
        __builtin_amdgcn_s_setprio(1);
#pragma unroll
        for (int s = 0; s < 4; s++) {
            int c = ((2 * s + hi) ^ swz) << 3;
            s16x8 v0 = *(const s16x8*)(vb0 + c);
            s16x8 v1 = *(const s16x8*)(vb1 + c);
            accY0 = __builtin_amdgcn_mfma_f32_32x32x16_bf16(v0, pb[s], accY0, 0, 0, 0);
            accY1 = __builtin_amdgcn_mfma_f32_32x32x16_bf16(v1, pb[s], accY1, 0, 0, 0);
        }
        __builtin_amdgcn_s_setprio(0);
    }
    // write y: accY reg 4r+d' -> d = d' + 8r + 4*hi (+32 for accY1); col q = ql (own lane)
    float linv = 1.f / lst;
    short* yrow = y + ((size_t)b * T + qrow) * 1024 + h * 64;
#pragma unroll
    for (int r = 0; r < 4; r++) {
        unsigned w0, w1, w2, w3;
        float a0 = accY0[4 * r] * linv, a1 = accY0[4 * r + 1] * linv;
        float a2 = accY0[4 * r + 2] * linv, a3 = accY0[4 * r + 3] * linv;
        float b0 = accY1[4 * r] * linv, b1 = accY1[4 * r + 1] * linv;
        float b2 = accY1[4 * r + 2] * linv, b3 = accY1[4 * r + 3] * linv;
        asm("v_cvt_pk_bf16_f32 %0, %1, %2" : "=v"(w0) : "v"(a0), "v"(a1));
        asm("v_cvt_pk_bf16_f32 %0, %1, %2" : "=v"(w1) : "v"(a2), "v"(a3));
        asm("v_cvt_pk_bf16_f32 %0, %1, %2" : "=v"(w2) : "v"(b0), "v"(b1));
        asm("v_cvt_pk_bf16_f32 %0, %1, %2" : "=v"(w3) : "v"(b2), "v"(b3));
        u32x2 p0; p0[0] = w0; p0[1] = w1;
        u32x2 p1; p1[0] = w2; p1[1] = w3;
        *(u32x2*)(yrow + 8 * r + 4 * hi)      = p0;
        *(u32x2*)(yrow + 32 + 8 * r + 4 * hi) = p1;
    }
}

extern "C" void kernel_launch(void* const* d_in, const int* in_sizes, int n_in,
                              void* d_out, int out_size, void* d_ws, size_t ws_size,
                              hipStream_t stream) {
    const float* x           = (const float*)d_in[0];
    const float* ln1_w       = (const float*)d_in[1];
    const float* ln1_b       = (const float*)d_in[2];
    const float* attn_w      = (const float*)d_in[3];
    const float* attn_b      = (const float*)d_in[4];
    const float* attn_proj_w = (const float*)d_in[5];
    const float* attn_proj_b = (const float*)d_in[6];
    const float* ln2_w       = (const float*)d_in[7];
    const float* ln2_b       = (const float*)d_in[8];
    const float* fc_w        = (const float*)d_in[9];
    const float* fc_b        = (const float*)d_in[10];
    const float* mlp_proj_w  = (const float*)d_in[11];
    const float* mlp_proj_b  = (const float*)d_in[12];

    const int M = 4096;  // B*T

    size_t off = 0;
    char* wsb = (char*)d_ws;
    auto alloc = [&](size_t bytes) {
        void* p = wsb + off;
        off += (bytes + 255) & ~(size_t)255;
        return p;
    };
    short* wt_attn  = (short*)alloc(3072ull * 1024 * 2);
    short* wt_proj  = (short*)alloc(1024ull * 1024 * 2);
    short* wt_fc    = (short*)alloc(4096ull * 1024 * 2);
    short* wt_mproj = (short*)alloc(1024ull * 4096 * 2);
    short* h1       = (short*)alloc((size_t)M * 1024 * 2);
    short* qkvb     = (short*)alloc((size_t)M * 3072 * 2);
    short* yb       = (short*)alloc((size_t)M * 1024 * 2);
    float* x1       = (float*)alloc((size_t)M * 1024 * 4);
    short* vtg      = (short*)alloc((size_t)M * 1024 * 2);   // V transposed
    short* h2       = qkvb;  // aliases qkv+y region (both dead by fc GEMM)

    // split-K partials for mlp_proj
    size_t base_off = off;
    int SK = 0;
    if (ws_size >= base_off + 4ull * M * 1024 * 4) SK = 4;
    else if (ws_size >= base_off + 2ull * M * 1024 * 4) SK = 2;
    float* part = (float*)(wsb + base_off);

    transpose_cast<<<dim3(3072 / 32, 1024 / 32), 256, 0, stream>>>(attn_w, wt_attn, 1024, 3072);
    transpose_cast<<<dim3(1024 / 32, 1024 / 32), 256, 0, stream>>>(attn_proj_w, wt_proj, 1024, 1024);
    transpose_cast<<<dim3(4096 / 32, 1024 / 32), 256, 0, stream>>>(fc_w, wt_fc, 1024, 4096);
    transpose_cast<<<dim3(1024 / 32, 4096 / 32), 256, 0, stream>>>(mlp_proj_w, wt_mproj, 4096, 1024);

    ln_kernel<<<M, 256, 0, stream>>>(x, ln1_w, ln1_b, h1);
    gemm_bt<short, false, false, true><<<dim3(3072 / 128, M / 128), 256, 0, stream>>>(
        h1, wt_attn, attn_b, nullptr, qkvb, M, 3072, 1024);
    vtrans_kernel<<<dim3(2048 / 32, 64), 256, 0, stream>>>(qkvb, vtg);
    attn_kernel<<<512, 256, 0, stream>>>(qkvb, vtg, yb);
    gemm_bt<float, false, true, false><<<dim3(1024 / 128, M / 128), 256, 0, stream>>>(
        yb, wt_proj, attn_proj_b, x, x1, M, 1024, 1024);
    ln_kernel<<<M, 256, 0, stream>>>(x1, ln2_w, ln2_b, h1);
    gemm_bt<short, true, false, false><<<dim3(4096 / 128, M / 128), 256, 0, stream>>>(
        h1, wt_fc, fc_b, nullptr, h2, M, 4096, 1024);

    if (SK == 4) {
        gemm_bt_sk<<<dim3(1024 / 128, M / 128, 4), 256, 0, stream>>>(
            h2, wt_mproj, part, M, 1024, 4096, 1024);
        reduce_sk<4><<<2048, 256, 0, stream>>>(part, mlp_proj_b, x1, (float*)d_out, M * 1024, 1024);
    } else if (SK == 2) {
        gemm_bt_sk<<<dim3(1024 / 128, M / 128, 2), 256, 0, stream>>>(
            h2, wt_mproj, part, M, 1024, 4096, 2048);
        reduce_sk<2><<<2048, 256, 0, stream>>>(part, mlp_proj_b, x1, (float*)d_out, M * 1024, 1024);
    } else {
        gemm_bt<float, false, true, false><<<dim3(1024 / 128, M / 128), 256, 0, stream>>>(
            h2, wt_mproj, mlp_proj_b, x1, (float*)d_out, M, 1024, 4096);
    }
}